// Round 1
// baseline (1422.250 us; speedup 1.0000x reference)
//
#include <hip/hip_runtime.h>

#define ALPHA 0.5f

// ---------------- CSR build ----------------

__global__ void k_hist(const int* __restrict__ rows, int nnz, int* __restrict__ cnt) {
  int e = blockIdx.x * blockDim.x + threadIdx.x;
  if (e < nnz) atomicAdd(&cnt[rows[e]], 1);
}

// per-chunk sums: chunk = 1024 elements, block = 256 threads
__global__ void k_chunk_sum(const int* __restrict__ cnt, int n, int* __restrict__ sums) {
  __shared__ int s[256];
  int base = blockIdx.x * 1024;
  int t = threadIdx.x;
  int v = 0;
  for (int k = 0; k < 4; k++) {
    int i = base + t + 256 * k;
    if (i < n) v += cnt[i];
  }
  s[t] = v; __syncthreads();
  for (int d = 128; d > 0; d >>= 1) {
    if (t < d) s[t] += s[t + d];
    __syncthreads();
  }
  if (t == 0) sums[blockIdx.x] = s[0];
}

// single-block exclusive scan of chunk sums (supports up to 512 chunks)
__global__ void k_scan_sums(const int* __restrict__ sums, int nChunks, int* __restrict__ off) {
  __shared__ int s[512];
  int t = threadIdx.x;
  int v = (t < nChunks) ? sums[t] : 0;
  s[t] = v; __syncthreads();
  for (int d = 1; d < 512; d <<= 1) {
    int x = (t >= d) ? s[t - d] : 0;
    __syncthreads();
    s[t] += x;
    __syncthreads();
  }
  if (t < nChunks) off[t] = s[t] - v;  // exclusive
}

__global__ void k_write_rowptr(const int* __restrict__ cnt, int n,
                               const int* __restrict__ off, int* __restrict__ rowptr) {
  __shared__ int s[256];
  int t = threadIdx.x;
  int base = blockIdx.x * 1024 + t * 4;
  int c0 = 0, c1 = 0, c2 = 0, c3 = 0;
  if (base + 0 < n) c0 = cnt[base + 0];
  if (base + 1 < n) c1 = cnt[base + 1];
  if (base + 2 < n) c2 = cnt[base + 2];
  if (base + 3 < n) c3 = cnt[base + 3];
  int tot = c0 + c1 + c2 + c3;
  s[t] = tot; __syncthreads();
  for (int d = 1; d < 256; d <<= 1) {
    int x = (t >= d) ? s[t - d] : 0;
    __syncthreads();
    s[t] += x;
    __syncthreads();
  }
  int excl = s[t] - tot + off[blockIdx.x];
  if (base + 0 < n) rowptr[base + 0] = excl;
  if (base + 1 < n) rowptr[base + 1] = excl + c0;
  if (base + 2 < n) rowptr[base + 2] = excl + c0 + c1;
  if (base + 3 < n) rowptr[base + 3] = excl + c0 + c1 + c2;
}

__global__ void k_scatter(const int* __restrict__ rows, const int* __restrict__ cols,
                          const float* __restrict__ vals, int nnz,
                          const int* __restrict__ rowptr, int* __restrict__ cur,
                          int* __restrict__ colS, float* __restrict__ valS) {
  int e = blockIdx.x * blockDim.x + threadIdx.x;
  if (e >= nnz) return;
  int r = rows[e];
  int pos = rowptr[r] + atomicAdd(&cur[r], 1);
  colS[pos] = cols[e];
  valS[pos] = vals[e];
}

// ---------------- SpMM: one wave per row, lane = dim ----------------

__device__ __forceinline__ const float* src_row(const float* u, const float* i, int split, int c) {
  return (c < split) ? (u + (size_t)c * 64) : (i + (size_t)(c - split) * 64);
}

__global__ __launch_bounds__(256) void k_spmm(
    const float* __restrict__ srcU, const float* __restrict__ srcI, int split,
    const float* __restrict__ e0U, const float* __restrict__ e0I,
    const int* __restrict__ rowptr, const int* __restrict__ cnt,
    const int* __restrict__ colS, const float* __restrict__ valS,
    float* __restrict__ dst, int n) {
  int wave = (int)((blockIdx.x * blockDim.x + threadIdx.x) >> 6);
  int lane = threadIdx.x & 63;
  if (wave >= n) return;
  int row = wave;
  int start = rowptr[row];
  int len = cnt[row];
  float acc = 0.f;
  for (int base = 0; base < len; base += 64) {
    int m = len - base; if (m > 64) m = 64;
    int c = 0; float v = 0.f;
    if (lane < m) {
      c = colS[start + base + lane];
      v = valS[start + base + lane];
    }
    int j = 0;
    for (; j + 4 <= m; j += 4) {
      int c0 = __shfl(c, j + 0), c1 = __shfl(c, j + 1), c2 = __shfl(c, j + 2), c3 = __shfl(c, j + 3);
      float v0 = __shfl(v, j + 0), v1 = __shfl(v, j + 1), v2 = __shfl(v, j + 2), v3 = __shfl(v, j + 3);
      float x0 = src_row(srcU, srcI, split, c0)[lane];
      float x1 = src_row(srcU, srcI, split, c1)[lane];
      float x2 = src_row(srcU, srcI, split, c2)[lane];
      float x3 = src_row(srcU, srcI, split, c3)[lane];
      acc = fmaf(v0, x0, acc);
      acc = fmaf(v1, x1, acc);
      acc = fmaf(v2, x2, acc);
      acc = fmaf(v3, x3, acc);
    }
    for (; j < m; j++) {
      int cj = __shfl(c, j);
      float vj = __shfl(v, j);
      acc = fmaf(vj, src_row(srcU, srcI, split, cj)[lane], acc);
    }
  }
  const float* e0 = (row < split) ? (e0U + (size_t)row * 64) : (e0I + (size_t)(row - split) * 64);
  dst[(size_t)row * 64 + lane] = acc + ALPHA * e0[lane];
}

// ---------------- output-row accumulation + final dot ----------------

__global__ void k_acc_init(const int* __restrict__ users, const int* __restrict__ items, int B,
                           const float* __restrict__ user_emb, const float* __restrict__ item_emb,
                           float* __restrict__ accU, float* __restrict__ accI) {
  int t = blockIdx.x * blockDim.x + threadIdx.x;
  int total = B * 64;
  if (t < total) {
    int b = t >> 6, d = t & 63;
    accU[t] = user_emb[(size_t)users[b] * 64 + d];
  } else if (t < 2 * total) {
    int t2 = t - total;
    int b = t2 >> 6, d = t2 & 63;
    accI[t2] = item_emb[(size_t)items[b] * 64 + d];
  }
}

__global__ void k_acc_add(const int* __restrict__ users, const int* __restrict__ items, int B,
                          int split, const float* __restrict__ buf, float w,
                          float* __restrict__ accU, float* __restrict__ accI) {
  int t = blockIdx.x * blockDim.x + threadIdx.x;
  int total = B * 64;
  if (t < total) {
    int b = t >> 6, d = t & 63;
    accU[t] += w * buf[(size_t)users[b] * 64 + d];
  } else if (t < 2 * total) {
    int t2 = t - total;
    int b = t2 >> 6, d = t2 & 63;
    accI[t2] += w * buf[(size_t)(split + items[b]) * 64 + d];
  }
}

__global__ void k_dot(const float* __restrict__ accU, const float* __restrict__ accI, int B,
                      float* __restrict__ out) {
  int wave = (int)((blockIdx.x * blockDim.x + threadIdx.x) >> 6);
  int lane = threadIdx.x & 63;
  if (wave >= B) return;
  float p = accU[(size_t)wave * 64 + lane] * accI[(size_t)wave * 64 + lane];
  for (int d = 32; d > 0; d >>= 1) p += __shfl_xor(p, d);
  if (lane == 0) out[wave] = p * (1.f / 16.f);  // (1/4)*(1/4) from the two layer-means
}

// ---------------- launch ----------------

extern "C" void kernel_launch(void* const* d_in, const int* in_sizes, int n_in,
                              void* d_out, int out_size, void* d_ws, size_t ws_size,
                              hipStream_t stream) {
  const int*   users     = (const int*)d_in[0];
  const int*   items     = (const int*)d_in[1];
  const int*   rows      = (const int*)d_in[2];
  const int*   cols      = (const int*)d_in[3];
  const float* vals      = (const float*)d_in[4];
  const float* user_emb  = (const float*)d_in[5];
  const float* item_emb  = (const float*)d_in[6];
  const float* user_emb0 = (const float*)d_in[7];
  const float* item_emb0 = (const float*)d_in[8];
  float* gamma = (float*)d_out;

  int B   = in_sizes[0];
  int nnz = in_sizes[2];
  int nU  = in_sizes[5] / 64;
  int nI  = in_sizes[6] / 64;
  int N   = nU + nI;
  int nChunks = (N + 1023) / 1024;

  float* ws = (float*)d_ws;
  size_t off = 0;
  float* bufA   = ws + off; off += (size_t)N * 64;
  float* bufB   = ws + off; off += (size_t)N * 64;
  float* valS   = ws + off; off += (size_t)nnz;
  int*   colS   = (int*)(ws + off); off += (size_t)nnz;
  int*   rowptr = (int*)(ws + off); off += N;
  int*   cnt    = (int*)(ws + off); off += N;
  int*   cnt2   = (int*)(ws + off); off += N;
  int*   sums   = (int*)(ws + off); off += nChunks;
  int*   soff   = (int*)(ws + off); off += nChunks;
  float* accU   = ws + off; off += (size_t)B * 64;
  float* accI   = ws + off; off += (size_t)B * 64;

  hipMemsetAsync(cnt,  0, (size_t)N * sizeof(int), stream);
  hipMemsetAsync(cnt2, 0, (size_t)N * sizeof(int), stream);

  const int tpb = 256;
  k_hist<<<(nnz + tpb - 1) / tpb, tpb, 0, stream>>>(rows, nnz, cnt);
  k_chunk_sum<<<nChunks, 256, 0, stream>>>(cnt, N, sums);
  k_scan_sums<<<1, 512, 0, stream>>>(sums, nChunks, soff);
  k_write_rowptr<<<nChunks, 256, 0, stream>>>(cnt, N, soff, rowptr);
  k_scatter<<<(nnz + tpb - 1) / tpb, tpb, 0, stream>>>(rows, cols, vals, nnz, rowptr, cnt2, colS, valS);

  int spmmBlocks = (N + 3) / 4;  // 4 waves (rows) per 256-thread block
  int accThreads = 2 * B * 64;
  int accBlocks = (accThreads + tpb - 1) / tpb;

  // layer 1: src = original embeddings (virtual concat), dst = bufA, weight 3
  k_spmm<<<spmmBlocks, 256, 0, stream>>>(user_emb, item_emb, nU, user_emb0, item_emb0,
                                         rowptr, cnt, colS, valS, bufA, N);
  k_acc_init<<<accBlocks, tpb, 0, stream>>>(users, items, B, user_emb, item_emb, accU, accI);
  k_acc_add<<<accBlocks, tpb, 0, stream>>>(users, items, B, nU, bufA, 3.f, accU, accI);

  // layer 2: src = bufA, dst = bufB, weight 2
  k_spmm<<<spmmBlocks, 256, 0, stream>>>(bufA, bufA + (size_t)nU * 64, nU, user_emb0, item_emb0,
                                         rowptr, cnt, colS, valS, bufB, N);
  k_acc_add<<<accBlocks, tpb, 0, stream>>>(users, items, B, nU, bufB, 2.f, accU, accI);

  // layer 3: src = bufB, dst = bufA, weight 1
  k_spmm<<<spmmBlocks, 256, 0, stream>>>(bufB, bufB + (size_t)nU * 64, nU, user_emb0, item_emb0,
                                         rowptr, cnt, colS, valS, bufA, N);
  k_acc_add<<<accBlocks, tpb, 0, stream>>>(users, items, B, nU, bufA, 1.f, accU, accI);

  k_dot<<<(B * 64 + tpb - 1) / tpb, tpb, 0, stream>>>(accU, accI, B, gamma);
}

// Round 2
// 1211.619 us; speedup vs baseline: 1.1738x; 1.1738x over previous
//
#include <hip/hip_runtime.h>

#define ALPHA 0.5f
#define BSHIFT 9                 // 512 rows per bucket
#define RPB 512
#define MAXB 1024                // LDS bucket-counter array size (>= nBuckets)

// ---------------- Phase 0: bucket counts ----------------

__global__ void k_bucket_count(const int* __restrict__ rows, int nnz, int* __restrict__ bcnt) {
  __shared__ int lcnt[MAXB];
  int t = threadIdx.x;
  for (int b = t; b < MAXB; b += 256) lcnt[b] = 0;
  __syncthreads();
  int stride = gridDim.x * 256;
  for (int e = blockIdx.x * 256 + t; e < nnz; e += stride)
    atomicAdd(&lcnt[rows[e] >> BSHIFT], 1);
  __syncthreads();
  for (int b = t; b < MAXB; b += 256) {
    int c = lcnt[b];
    if (c) atomicAdd(&bcnt[b], c);
  }
}

// ---------------- Phase 1: scan bucket counts -> bucketPtr, bucketCur ----------------

__global__ void k_scan_buckets(const int* __restrict__ bcnt, int nb,
                               int* __restrict__ bptr, int* __restrict__ bcur) {
  __shared__ int s[MAXB];
  int t = threadIdx.x;            // 1024 threads
  int v = (t < nb) ? bcnt[t] : 0;
  s[t] = v; __syncthreads();
  for (int d = 1; d < MAXB; d <<= 1) {
    int x = (t >= d) ? s[t - d] : 0;
    __syncthreads();
    s[t] += x;
    __syncthreads();
  }
  if (t < nb) {
    int excl = s[t] - v;
    bptr[t] = excl;
    bcur[t] = excl;
    bptr[t + 1] = s[t];           // inclusive -> bptr[nb] = total (last thread wins ordering ok)
  }
  if (t == 0) bptr[0] = 0;
}

// ---------------- Phase 2: partition edges into buckets ----------------
// chunk = 8192 edges per block

__global__ __launch_bounds__(256) void k_partition(
    const int* __restrict__ rows, const int* __restrict__ cols, const float* __restrict__ vals,
    int nnz, int* __restrict__ bcur,
    int* __restrict__ pRow, int* __restrict__ pCol, float* __restrict__ pVal) {
  __shared__ int lcnt[MAXB];
  __shared__ int lbase[MAXB];
  int t = threadIdx.x;
  for (int b = t; b < MAXB; b += 256) lcnt[b] = 0;
  __syncthreads();
  int base = blockIdx.x * 8192;
  for (int k = 0; k < 32; k++) {
    int e = base + k * 256 + t;
    if (e < nnz) atomicAdd(&lcnt[rows[e] >> BSHIFT], 1);
  }
  __syncthreads();
  for (int b = t; b < MAXB; b += 256) {
    int c = lcnt[b];
    lbase[b] = c ? atomicAdd(&bcur[b], c) : 0;
    lcnt[b] = 0;
  }
  __syncthreads();
  for (int k = 0; k < 32; k++) {
    int e = base + k * 256 + t;
    if (e < nnz) {
      int r = rows[e];
      int b = r >> BSHIFT;
      int p = lbase[b] + atomicAdd(&lcnt[b], 1);
      pRow[p] = r;
      pCol[p] = cols[e];
      pVal[p] = vals[e];
    }
  }
}

// ---------------- Phase 3: per-bucket CSR build (rowptr, cnt, colval) ----------------

__global__ __launch_bounds__(256) void k_build_csr(
    const int* __restrict__ bptr,
    const int* __restrict__ pRow, const int* __restrict__ pCol, const float* __restrict__ pVal,
    int N, int* __restrict__ rowptr, int* __restrict__ cnt, int2* __restrict__ colval) {
  __shared__ int lcnt[RPB];
  __shared__ int lofs[RPB];
  __shared__ int scanbuf[256];
  int t = threadIdx.x;
  int b = blockIdx.x;
  int r0 = b << BSHIFT;
  int rCount = N - r0; if (rCount > RPB) rCount = RPB;
  int eBeg = bptr[b], eEnd = bptr[b + 1];

  lcnt[t] = 0; lcnt[t + 256] = 0;
  __syncthreads();
  for (int e = eBeg + t; e < eEnd; e += 256)
    atomicAdd(&lcnt[pRow[e] - r0], 1);
  __syncthreads();
  // block scan over 512 counters (2 per thread)
  int c0 = lcnt[2 * t], c1 = lcnt[2 * t + 1];
  int pairSum = c0 + c1;
  scanbuf[t] = pairSum; __syncthreads();
  for (int d = 1; d < 256; d <<= 1) {
    int x = (t >= d) ? scanbuf[t - d] : 0;
    __syncthreads();
    scanbuf[t] += x;
    __syncthreads();
  }
  int excl = scanbuf[t] - pairSum;
  lofs[2 * t] = excl;
  lofs[2 * t + 1] = excl + c0;
  // publish rowptr / cnt
  if (2 * t < rCount)     { rowptr[r0 + 2 * t]     = eBeg + lofs[2 * t];     cnt[r0 + 2 * t]     = c0; }
  if (2 * t + 1 < rCount) { rowptr[r0 + 2 * t + 1] = eBeg + lofs[2 * t + 1]; cnt[r0 + 2 * t + 1] = c1; }
  lcnt[2 * t] = 0; lcnt[2 * t + 1] = 0;
  __syncthreads();
  // scatter into CSR slots (destination window ~eEnd-eBeg entries: L2-resident)
  for (int e = eBeg + t; e < eEnd; e += 256) {
    int r = pRow[e] - r0;
    int p = eBeg + lofs[r] + atomicAdd(&lcnt[r], 1);
    int2 cv; cv.x = pCol[e]; cv.y = __float_as_int(pVal[e]);
    colval[p] = cv;
  }
}

// ---------------- SpMM: one wave per row, lane = dim ----------------

__global__ __launch_bounds__(256) void k_spmm(
    const float* __restrict__ srcU, const float* __restrict__ srcI, int split,
    const float* __restrict__ e0U, const float* __restrict__ e0I,
    const int* __restrict__ rowptr, const int* __restrict__ cnt,
    const int2* __restrict__ colval,
    float* __restrict__ dst, int n) {
  int wave = (int)((blockIdx.x * blockDim.x + threadIdx.x) >> 6);
  int lane = threadIdx.x & 63;
  if (wave >= n) return;
  int row = wave;
  int start = __builtin_amdgcn_readfirstlane(rowptr[row]);
  int len   = __builtin_amdgcn_readfirstlane(cnt[row]);
  const int2* cv = colval + start;
  float acc = 0.f;
  int j = 0;
  for (; j + 8 <= len; j += 8) {
#pragma unroll
    for (int u = 0; u < 8; u++) {
      int2 e = cv[j + u];
      const float* s = (e.x < split) ? (srcU + (size_t)e.x * 64)
                                     : (srcI + (size_t)(e.x - split) * 64);
      acc = fmaf(__int_as_float(e.y), s[lane], acc);
    }
  }
  for (; j < len; j++) {
    int2 e = cv[j];
    const float* s = (e.x < split) ? (srcU + (size_t)e.x * 64)
                                   : (srcI + (size_t)(e.x - split) * 64);
    acc = fmaf(__int_as_float(e.y), s[lane], acc);
  }
  const float* e0 = (row < split) ? (e0U + (size_t)row * 64) : (e0I + (size_t)(row - split) * 64);
  dst[(size_t)row * 64 + lane] = acc + ALPHA * e0[lane];
}

// ---------------- output-row accumulation + final dot ----------------

__global__ void k_acc_init(const int* __restrict__ users, const int* __restrict__ items, int B,
                           const float* __restrict__ user_emb, const float* __restrict__ item_emb,
                           float* __restrict__ accU, float* __restrict__ accI) {
  int t = blockIdx.x * blockDim.x + threadIdx.x;
  int total = B * 64;
  if (t < total) {
    int b = t >> 6, d = t & 63;
    accU[t] = user_emb[(size_t)users[b] * 64 + d];
  } else if (t < 2 * total) {
    int t2 = t - total;
    int b = t2 >> 6, d = t2 & 63;
    accI[t2] = item_emb[(size_t)items[b] * 64 + d];
  }
}

__global__ void k_acc_add(const int* __restrict__ users, const int* __restrict__ items, int B,
                          int split, const float* __restrict__ buf, float w,
                          float* __restrict__ accU, float* __restrict__ accI) {
  int t = blockIdx.x * blockDim.x + threadIdx.x;
  int total = B * 64;
  if (t < total) {
    int b = t >> 6, d = t & 63;
    accU[t] += w * buf[(size_t)users[b] * 64 + d];
  } else if (t < 2 * total) {
    int t2 = t - total;
    int b = t2 >> 6, d = t2 & 63;
    accI[t2] += w * buf[(size_t)(split + items[b]) * 64 + d];
  }
}

__global__ void k_dot(const float* __restrict__ accU, const float* __restrict__ accI, int B,
                      float* __restrict__ out) {
  int wave = (int)((blockIdx.x * blockDim.x + threadIdx.x) >> 6);
  int lane = threadIdx.x & 63;
  if (wave >= B) return;
  float p = accU[(size_t)wave * 64 + lane] * accI[(size_t)wave * 64 + lane];
  for (int d = 32; d > 0; d >>= 1) p += __shfl_xor(p, d);
  if (lane == 0) out[wave] = p * (1.f / 16.f);  // (1/4) layer mean x (1/4) weight normalization
}

// ---------------- launch ----------------

extern "C" void kernel_launch(void* const* d_in, const int* in_sizes, int n_in,
                              void* d_out, int out_size, void* d_ws, size_t ws_size,
                              hipStream_t stream) {
  const int*   users     = (const int*)d_in[0];
  const int*   items     = (const int*)d_in[1];
  const int*   rows      = (const int*)d_in[2];
  const int*   cols      = (const int*)d_in[3];
  const float* vals      = (const float*)d_in[4];
  const float* user_emb  = (const float*)d_in[5];
  const float* item_emb  = (const float*)d_in[6];
  const float* user_emb0 = (const float*)d_in[7];
  const float* item_emb0 = (const float*)d_in[8];
  float* gamma = (float*)d_out;

  int B   = in_sizes[0];
  int nnz = in_sizes[2];
  int nU  = in_sizes[5] / 64;
  int nI  = in_sizes[6] / 64;
  int N   = nU + nI;
  int nb  = (N + RPB - 1) >> BSHIFT;   // number of buckets

  float* ws = (float*)d_ws;
  size_t off = 0;
  float* bufA   = ws + off; off += (size_t)N * 64;
  float* bufB   = ws + off; off += (size_t)N * 64;
  // partition payload overlaid on bufB (dead until layer-2 SpMM output)
  int*   pRow = (int*)bufB;
  int*   pCol = pRow + nnz;
  float* pVal = (float*)(pCol + nnz);
  int2*  colval = (int2*)(ws + off); off += (size_t)2 * nnz;
  int*   rowptr = (int*)(ws + off); off += N;
  int*   cnt    = (int*)(ws + off); off += N;
  int*   bcnt   = (int*)(ws + off); off += MAXB;
  int*   bptr   = (int*)(ws + off); off += MAXB + 1;
  int*   bcur   = (int*)(ws + off); off += MAXB;
  float* accU   = ws + off; off += (size_t)B * 64;
  float* accI   = ws + off; off += (size_t)B * 64;

  hipMemsetAsync(bcnt, 0, MAXB * sizeof(int), stream);

  const int tpb = 256;
  k_bucket_count<<<512, tpb, 0, stream>>>(rows, nnz, bcnt);
  k_scan_buckets<<<1, MAXB, 0, stream>>>(bcnt, nb, bptr, bcur);
  k_partition<<<(nnz + 8191) / 8192, tpb, 0, stream>>>(rows, cols, vals, nnz, bcur, pRow, pCol, pVal);
  k_build_csr<<<nb, tpb, 0, stream>>>(bptr, pRow, pCol, pVal, N, rowptr, cnt, colval);

  int spmmBlocks = (N + 3) / 4;            // 4 waves (rows) per 256-thread block
  int accThreads = 2 * B * 64;
  int accBlocks = (accThreads + tpb - 1) / tpb;

  // layer 1: src = original embeddings (virtual concat), dst = bufA, weight 3
  k_spmm<<<spmmBlocks, 256, 0, stream>>>(user_emb, item_emb, nU, user_emb0, item_emb0,
                                         rowptr, cnt, colval, bufA, N);
  k_acc_init<<<accBlocks, tpb, 0, stream>>>(users, items, B, user_emb, item_emb, accU, accI);
  k_acc_add<<<accBlocks, tpb, 0, stream>>>(users, items, B, nU, bufA, 3.f, accU, accI);

  // layer 2: src = bufA, dst = bufB (partition payload now dead), weight 2
  k_spmm<<<spmmBlocks, 256, 0, stream>>>(bufA, bufA + (size_t)nU * 64, nU, user_emb0, item_emb0,
                                         rowptr, cnt, colval, bufB, N);
  k_acc_add<<<accBlocks, tpb, 0, stream>>>(users, items, B, nU, bufB, 2.f, accU, accI);

  // layer 3: src = bufB, dst = bufA, weight 1
  k_spmm<<<spmmBlocks, 256, 0, stream>>>(bufB, bufB + (size_t)nU * 64, nU, user_emb0, item_emb0,
                                         rowptr, cnt, colval, bufA, N);
  k_acc_add<<<accBlocks, tpb, 0, stream>>>(users, items, B, nU, bufA, 1.f, accU, accI);

  k_dot<<<(B * 64 + tpb - 1) / tpb, tpb, 0, stream>>>(accU, accI, B, gamma);
}

// Round 3
// 1009.918 us; speedup vs baseline: 1.4083x; 1.1997x over previous
//
#include <hip/hip_runtime.h>

#define ALPHA 0.5f
#define BSHIFT 11                // 2048 rows per bucket
#define RPB 2048
#define MAXB 256                 // >= nBuckets (147)
#define CHUNK 8192               // edges per partition block

// ---------------- Phase 0: bucket counts ----------------

__global__ __launch_bounds__(256) void k_bucket_count(const int* __restrict__ rows, int nnz,
                                                      int* __restrict__ bcnt) {
  __shared__ int lcnt[MAXB];
  int t = threadIdx.x;
  if (t < MAXB) lcnt[t] = 0;
  __syncthreads();
  int stride = gridDim.x * 256;
  for (int e = blockIdx.x * 256 + t; e < nnz; e += stride)
    atomicAdd(&lcnt[rows[e] >> BSHIFT], 1);
  __syncthreads();
  if (t < MAXB) {
    int c = lcnt[t];
    if (c) atomicAdd(&bcnt[t], c);
  }
}

// ---------------- Phase 1: scan bucket counts -> bptr, bcur ----------------

__global__ void k_scan_buckets(const int* __restrict__ bcnt, int nb,
                               int* __restrict__ bptr, int* __restrict__ bcur) {
  __shared__ int s[256];
  int t = threadIdx.x;
  int v = (t < nb) ? bcnt[t] : 0;
  s[t] = v; __syncthreads();
  for (int d = 1; d < 256; d <<= 1) {
    int x = (t >= d) ? s[t - d] : 0;
    __syncthreads();
    s[t] += x;
    __syncthreads();
  }
  if (t < nb) {
    int excl = s[t] - v;
    bptr[t] = excl;
    bcur[t] = excl;
  }
  if (t == 0) bptr[nb] = s[255];   // total
}

// ---------------- Phase 2: partition edges into buckets (packed 8B payload) ----------------

__global__ __launch_bounds__(256) void k_partition(
    const int* __restrict__ rows, const int* __restrict__ cols, const float* __restrict__ vals,
    int nnz, int* __restrict__ bcur, uint2* __restrict__ pPay) {
  __shared__ int lcnt[MAXB];
  __shared__ int lbase[MAXB];
  int t = threadIdx.x;
  if (t < MAXB) lcnt[t] = 0;
  __syncthreads();
  int base = blockIdx.x * CHUNK;
  int end = nnz < base + CHUNK ? nnz : base + CHUNK;
  for (int e = base + t; e < end; e += 256)
    atomicAdd(&lcnt[rows[e] >> BSHIFT], 1);
  __syncthreads();
  if (t < MAXB) {
    int c = lcnt[t];
    lbase[t] = c ? atomicAdd(&bcur[t], c) : 0;
    lcnt[t] = 0;
  }
  __syncthreads();
  for (int e = base + t; e < end; e += 256) {
    int r = rows[e];
    int b = r >> BSHIFT;
    int p = lbase[b] + atomicAdd(&lcnt[b], 1);
    uint2 pay;
    pay.x = ((unsigned)(r & (RPB - 1)) << 20) | (unsigned)cols[e];
    pay.y = __float_as_uint(vals[e]);
    pPay[p] = pay;
  }
}

// ---------------- Phase 3: per-bucket CSR build ----------------

__global__ __launch_bounds__(256) void k_build_csr(
    const int* __restrict__ bptr, const uint2* __restrict__ pPay, int N,
    int* __restrict__ rowptr, int* __restrict__ cnt, int2* __restrict__ colval) {
  __shared__ int lcnt[RPB];        // 8 KB: counts -> cursors
  __shared__ int scanbuf[256];
  int t = threadIdx.x;
  int b = blockIdx.x;
  int r0 = b << BSHIFT;
  int rCount = N - r0; if (rCount > RPB) rCount = RPB;
  int eBeg = bptr[b], eEnd = bptr[b + 1];

  for (int r = t; r < RPB; r += 256) lcnt[r] = 0;
  __syncthreads();
  for (int e = eBeg + t; e < eEnd; e += 256)
    atomicAdd(&lcnt[pPay[e].x >> 20], 1);
  __syncthreads();
  // publish cnt
  for (int r = t; r < rCount; r += 256) cnt[r0 + r] = lcnt[r];
  // local serial scan: thread t owns lcnt[8t .. 8t+8)
  int v8[8]; int s = 0;
#pragma unroll
  for (int k = 0; k < 8; k++) {
    int x = lcnt[8 * t + k];
    v8[k] = s; s += x;
  }
  scanbuf[t] = s; __syncthreads();   // barrier also protects the lcnt reads above
  for (int d = 1; d < 256; d <<= 1) {
    int x = (t >= d) ? scanbuf[t - d] : 0;
    __syncthreads();
    scanbuf[t] += x;
    __syncthreads();
  }
  int blockExcl = scanbuf[t] - s;
#pragma unroll
  for (int k = 0; k < 8; k++) lcnt[8 * t + k] = blockExcl + v8[k];
  __syncthreads();
  // publish rowptr
  for (int r = t; r < rCount; r += 256) rowptr[r0 + r] = eBeg + lcnt[r];
  __syncthreads();
  // scatter into final CSR slots (window ~273 KB: L2-resident)
  for (int e = eBeg + t; e < eEnd; e += 256) {
    uint2 pay = pPay[e];
    int r = (int)(pay.x >> 20);
    int p = eBeg + atomicAdd(&lcnt[r], 1);
    int2 cv; cv.x = (int)(pay.x & 0xFFFFFu); cv.y = (int)pay.y;
    colval[p] = cv;
  }
}

// ---------------- SpMM: one wave per row, lane = dim ----------------

__global__ __launch_bounds__(256) void k_spmm(
    const float* __restrict__ srcU, const float* __restrict__ srcI, int split,
    const float* __restrict__ e0U, const float* __restrict__ e0I,
    const int* __restrict__ rowptr, const int* __restrict__ cnt,
    const int2* __restrict__ colval,
    float* __restrict__ dst, int n) {
  int wave = (int)((blockIdx.x * blockDim.x + threadIdx.x) >> 6);
  int lane = threadIdx.x & 63;
  if (wave >= n) return;
  int row = wave;
  int start = __builtin_amdgcn_readfirstlane(rowptr[row]);
  int len   = __builtin_amdgcn_readfirstlane(cnt[row]);
  const int2* cv = colval + start;
  float acc0 = 0.f, acc1 = 0.f;
  int j = 0;
  for (; j + 8 <= len; j += 8) {
#pragma unroll
    for (int u = 0; u < 8; u += 2) {
      int2 ea = cv[j + u];
      int2 eb = cv[j + u + 1];
      const float* sa = (ea.x < split) ? (srcU + (size_t)ea.x * 64)
                                       : (srcI + (size_t)(ea.x - split) * 64);
      const float* sb = (eb.x < split) ? (srcU + (size_t)eb.x * 64)
                                       : (srcI + (size_t)(eb.x - split) * 64);
      acc0 = fmaf(__int_as_float(ea.y), sa[lane], acc0);
      acc1 = fmaf(__int_as_float(eb.y), sb[lane], acc1);
    }
  }
  for (; j < len; j++) {
    int2 e = cv[j];
    const float* sp = (e.x < split) ? (srcU + (size_t)e.x * 64)
                                    : (srcI + (size_t)(e.x - split) * 64);
    acc0 = fmaf(__int_as_float(e.y), sp[lane], acc0);
  }
  float acc = acc0 + acc1;
  const float* e0 = (row < split) ? (e0U + (size_t)row * 64) : (e0I + (size_t)(row - split) * 64);
  dst[(size_t)row * 64 + lane] = acc + ALPHA * e0[lane];
}

// ---------------- output-row accumulation + final dot ----------------

__global__ void k_acc_init(const int* __restrict__ users, const int* __restrict__ items, int B,
                           const float* __restrict__ user_emb, const float* __restrict__ item_emb,
                           float* __restrict__ accU, float* __restrict__ accI) {
  int t = blockIdx.x * blockDim.x + threadIdx.x;
  int total = B * 64;
  if (t < total) {
    int b = t >> 6, d = t & 63;
    accU[t] = user_emb[(size_t)users[b] * 64 + d];
  } else if (t < 2 * total) {
    int t2 = t - total;
    int b = t2 >> 6, d = t2 & 63;
    accI[t2] = item_emb[(size_t)items[b] * 64 + d];
  }
}

__global__ void k_acc_add(const int* __restrict__ users, const int* __restrict__ items, int B,
                          int split, const float* __restrict__ buf, float w,
                          float* __restrict__ accU, float* __restrict__ accI) {
  int t = blockIdx.x * blockDim.x + threadIdx.x;
  int total = B * 64;
  if (t < total) {
    int b = t >> 6, d = t & 63;
    accU[t] += w * buf[(size_t)users[b] * 64 + d];
  } else if (t < 2 * total) {
    int t2 = t - total;
    int b = t2 >> 6, d = t2 & 63;
    accI[t2] += w * buf[(size_t)(split + items[b]) * 64 + d];
  }
}

__global__ void k_dot(const float* __restrict__ accU, const float* __restrict__ accI, int B,
                      float* __restrict__ out) {
  int wave = (int)((blockIdx.x * blockDim.x + threadIdx.x) >> 6);
  int lane = threadIdx.x & 63;
  if (wave >= B) return;
  float p = accU[(size_t)wave * 64 + lane] * accI[(size_t)wave * 64 + lane];
  for (int d = 32; d > 0; d >>= 1) p += __shfl_xor(p, d);
  if (lane == 0) out[wave] = p * (1.f / 16.f);  // (1/4) layer mean x (1/4) weight norm
}

// ---------------- launch ----------------

extern "C" void kernel_launch(void* const* d_in, const int* in_sizes, int n_in,
                              void* d_out, int out_size, void* d_ws, size_t ws_size,
                              hipStream_t stream) {
  const int*   users     = (const int*)d_in[0];
  const int*   items     = (const int*)d_in[1];
  const int*   rows      = (const int*)d_in[2];
  const int*   cols      = (const int*)d_in[3];
  const float* vals      = (const float*)d_in[4];
  const float* user_emb  = (const float*)d_in[5];
  const float* item_emb  = (const float*)d_in[6];
  const float* user_emb0 = (const float*)d_in[7];
  const float* item_emb0 = (const float*)d_in[8];
  float* gamma = (float*)d_out;

  int B   = in_sizes[0];
  int nnz = in_sizes[2];
  int nU  = in_sizes[5] / 64;
  int nI  = in_sizes[6] / 64;
  int N   = nU + nI;
  int nb  = (N + RPB - 1) >> BSHIFT;   // 147 buckets

  float* ws = (float*)d_ws;
  size_t off = 0;
  float* bufA   = ws + off; off += (size_t)N * 64;
  float* bufB   = ws + off; off += (size_t)N * 64;
  uint2* pPay   = (uint2*)bufB;        // payload overlaid on bufB (dead until layer-2 output)
  int2*  colval = (int2*)(ws + off); off += (size_t)2 * nnz;
  int*   rowptr = (int*)(ws + off); off += N;
  int*   cnt    = (int*)(ws + off); off += N;
  int*   bcnt   = (int*)(ws + off); off += MAXB;
  int*   bptr   = (int*)(ws + off); off += MAXB + 1;
  int*   bcur   = (int*)(ws + off); off += MAXB;
  float* accU   = ws + off; off += (size_t)B * 64;
  float* accI   = ws + off; off += (size_t)B * 64;

  hipMemsetAsync(bcnt, 0, MAXB * sizeof(int), stream);

  const int tpb = 256;
  k_bucket_count<<<512, tpb, 0, stream>>>(rows, nnz, bcnt);
  k_scan_buckets<<<1, 256, 0, stream>>>(bcnt, nb, bptr, bcur);
  k_partition<<<(nnz + CHUNK - 1) / CHUNK, tpb, 0, stream>>>(rows, cols, vals, nnz, bcur, pPay);
  k_build_csr<<<nb, tpb, 0, stream>>>(bptr, pPay, N, rowptr, cnt, colval);

  int spmmBlocks = (N + 3) / 4;            // 4 waves (rows) per 256-thread block
  int accThreads = 2 * B * 64;
  int accBlocks = (accThreads + tpb - 1) / tpb;

  // layer 1: src = original embeddings (virtual concat), dst = bufA, weight 3
  k_spmm<<<spmmBlocks, 256, 0, stream>>>(user_emb, item_emb, nU, user_emb0, item_emb0,
                                         rowptr, cnt, colval, bufA, N);
  k_acc_init<<<accBlocks, tpb, 0, stream>>>(users, items, B, user_emb, item_emb, accU, accI);
  k_acc_add<<<accBlocks, tpb, 0, stream>>>(users, items, B, nU, bufA, 3.f, accU, accI);

  // layer 2: src = bufA, dst = bufB (payload now dead), weight 2
  k_spmm<<<spmmBlocks, 256, 0, stream>>>(bufA, bufA + (size_t)nU * 64, nU, user_emb0, item_emb0,
                                         rowptr, cnt, colval, bufB, N);
  k_acc_add<<<accBlocks, tpb, 0, stream>>>(users, items, B, nU, bufB, 2.f, accU, accI);

  // layer 3: src = bufB, dst = bufA, weight 1
  k_spmm<<<spmmBlocks, 256, 0, stream>>>(bufB, bufB + (size_t)nU * 64, nU, user_emb0, item_emb0,
                                         rowptr, cnt, colval, bufA, N);
  k_acc_add<<<accBlocks, tpb, 0, stream>>>(users, items, B, nU, bufA, 1.f, accU, accI);

  k_dot<<<(B * 64 + tpb - 1) / tpb, tpb, 0, stream>>>(accU, accI, B, gamma);
}

// Round 4
// 758.365 us; speedup vs baseline: 1.8754x; 1.3317x over previous
//
#include <hip/hip_runtime.h>

#define ALPHA 0.5f
#define BSHIFT 11                // 2048 rows per bucket
#define RPB 2048
#define MAXB 256                 // >= nBuckets (147)
#define CHUNK 8192               // edges per partition block

// ---------------- bf16 helpers ----------------

__device__ __forceinline__ float bf2f(unsigned short u) {
  return __uint_as_float((unsigned)u << 16);
}
__device__ __forceinline__ unsigned short f2bf(float f) {
  unsigned u = __float_as_uint(f);
  u += 0x7fffu + ((u >> 16) & 1u);   // round-to-nearest-even
  return (unsigned short)(u >> 16);
}

// ---------------- input conversion: concat(user_emb,item_emb) -> bf16 ----------------

__global__ __launch_bounds__(256) void k_convert(const float* __restrict__ uE,
                                                 const float* __restrict__ iE,
                                                 int nU64, int nTot,
                                                 unsigned short* __restrict__ out) {
  int i = (blockIdx.x * 256 + threadIdx.x) * 4;
  if (i >= nTot) return;
  const float* src = (i < nU64) ? (uE + i) : (iE + (i - nU64));
  float4 v = *(const float4*)src;
  ushort4 o;
  o.x = f2bf(v.x); o.y = f2bf(v.y); o.z = f2bf(v.z); o.w = f2bf(v.w);
  *(ushort4*)(out + i) = o;
}

// ---------------- Phase 0: bucket counts ----------------

__global__ __launch_bounds__(256) void k_bucket_count(const int* __restrict__ rows, int nnz,
                                                      int* __restrict__ bcnt) {
  __shared__ int lcnt[MAXB];
  int t = threadIdx.x;
  if (t < MAXB) lcnt[t] = 0;
  __syncthreads();
  int stride = gridDim.x * 256;
  for (int e = blockIdx.x * 256 + t; e < nnz; e += stride)
    atomicAdd(&lcnt[rows[e] >> BSHIFT], 1);
  __syncthreads();
  if (t < MAXB) {
    int c = lcnt[t];
    if (c) atomicAdd(&bcnt[t], c);
  }
}

// ---------------- Phase 1: scan bucket counts -> bptr, bcur ----------------

__global__ void k_scan_buckets(const int* __restrict__ bcnt, int nb,
                               int* __restrict__ bptr, int* __restrict__ bcur) {
  __shared__ int s[256];
  int t = threadIdx.x;
  int v = (t < nb) ? bcnt[t] : 0;
  s[t] = v; __syncthreads();
  for (int d = 1; d < 256; d <<= 1) {
    int x = (t >= d) ? s[t - d] : 0;
    __syncthreads();
    s[t] += x;
    __syncthreads();
  }
  if (t < nb) {
    int excl = s[t] - v;
    bptr[t] = excl;
    bcur[t] = excl;
  }
  if (t == 0) bptr[nb] = s[255];   // total
}

// ---------------- Phase 2: partition edges into buckets (packed 8B payload) ----------------

__global__ __launch_bounds__(256) void k_partition(
    const int* __restrict__ rows, const int* __restrict__ cols, const float* __restrict__ vals,
    int nnz, int* __restrict__ bcur, uint2* __restrict__ pPay) {
  __shared__ int lcnt[MAXB];
  __shared__ int lbase[MAXB];
  int t = threadIdx.x;
  if (t < MAXB) lcnt[t] = 0;
  __syncthreads();
  int base = blockIdx.x * CHUNK;
  int end = nnz < base + CHUNK ? nnz : base + CHUNK;
  for (int e = base + t; e < end; e += 256)
    atomicAdd(&lcnt[rows[e] >> BSHIFT], 1);
  __syncthreads();
  if (t < MAXB) {
    int c = lcnt[t];
    lbase[t] = c ? atomicAdd(&bcur[t], c) : 0;
    lcnt[t] = 0;
  }
  __syncthreads();
  for (int e = base + t; e < end; e += 256) {
    int r = rows[e];
    int b = r >> BSHIFT;
    int p = lbase[b] + atomicAdd(&lcnt[b], 1);
    uint2 pay;
    pay.x = ((unsigned)(r & (RPB - 1)) << 20) | (unsigned)cols[e];
    pay.y = __float_as_uint(vals[e]);
    pPay[p] = pay;
  }
}

// ---------------- Phase 3: per-bucket CSR build ----------------

__global__ __launch_bounds__(256) void k_build_csr(
    const int* __restrict__ bptr, const uint2* __restrict__ pPay, int N,
    int* __restrict__ rowptr, int* __restrict__ cnt, int2* __restrict__ colval) {
  __shared__ int lcnt[RPB];        // 8 KB: counts -> cursors
  __shared__ int scanbuf[256];
  int t = threadIdx.x;
  int b = blockIdx.x;
  int r0 = b << BSHIFT;
  int rCount = N - r0; if (rCount > RPB) rCount = RPB;
  int eBeg = bptr[b], eEnd = bptr[b + 1];

  for (int r = t; r < RPB; r += 256) lcnt[r] = 0;
  __syncthreads();
  for (int e = eBeg + t; e < eEnd; e += 256)
    atomicAdd(&lcnt[pPay[e].x >> 20], 1);
  __syncthreads();
  for (int r = t; r < rCount; r += 256) cnt[r0 + r] = lcnt[r];
  int v8[8]; int s = 0;
#pragma unroll
  for (int k = 0; k < 8; k++) {
    int x = lcnt[8 * t + k];
    v8[k] = s; s += x;
  }
  scanbuf[t] = s; __syncthreads();
  for (int d = 1; d < 256; d <<= 1) {
    int x = (t >= d) ? scanbuf[t - d] : 0;
    __syncthreads();
    scanbuf[t] += x;
    __syncthreads();
  }
  int blockExcl = scanbuf[t] - s;
#pragma unroll
  for (int k = 0; k < 8; k++) lcnt[8 * t + k] = blockExcl + v8[k];
  __syncthreads();
  for (int r = t; r < rCount; r += 256) rowptr[r0 + r] = eBeg + lcnt[r];
  __syncthreads();
  for (int e = eBeg + t; e < eEnd; e += 256) {
    uint2 pay = pPay[e];
    int r = (int)(pay.x >> 20);
    int p = eBeg + atomicAdd(&lcnt[r], 1);
    int2 cv; cv.x = (int)(pay.x & 0xFFFFFu); cv.y = (int)pay.y;
    colval[p] = cv;
  }
}

// ---------------- SpMM (bf16 src/dst): one wave per row, lane = dim ----------------

__global__ __launch_bounds__(256) void k_spmm(
    const unsigned short* __restrict__ src,
    const float* __restrict__ e0U, const float* __restrict__ e0I, int split,
    const int* __restrict__ rowptr, const int* __restrict__ cnt,
    const int2* __restrict__ colval,
    unsigned short* __restrict__ dst, int n) {
  int wave = (int)((blockIdx.x * blockDim.x + threadIdx.x) >> 6);
  int lane = threadIdx.x & 63;
  if (wave >= n) return;
  int row = wave;
  int start = __builtin_amdgcn_readfirstlane(rowptr[row]);
  int len   = __builtin_amdgcn_readfirstlane(cnt[row]);
  const int2* cv = colval + start;
  float acc0 = 0.f, acc1 = 0.f;
  int j = 0;
  for (; j + 8 <= len; j += 8) {
#pragma unroll
    for (int u = 0; u < 8; u += 2) {
      int2 ea = cv[j + u];
      int2 eb = cv[j + u + 1];
      float xa = bf2f(src[(size_t)ea.x * 64 + lane]);
      float xb = bf2f(src[(size_t)eb.x * 64 + lane]);
      acc0 = fmaf(__int_as_float(ea.y), xa, acc0);
      acc1 = fmaf(__int_as_float(eb.y), xb, acc1);
    }
  }
  for (; j < len; j++) {
    int2 e = cv[j];
    acc0 = fmaf(__int_as_float(e.y), bf2f(src[(size_t)e.x * 64 + lane]), acc0);
  }
  float acc = acc0 + acc1;
  const float* e0 = (row < split) ? (e0U + (size_t)row * 64) : (e0I + (size_t)(row - split) * 64);
  dst[(size_t)row * 64 + lane] = f2bf(acc + ALPHA * e0[lane]);
}

// ---------------- output-row accumulation ----------------

__global__ void k_acc_init(const int* __restrict__ users, const int* __restrict__ items, int B,
                           const float* __restrict__ user_emb, const float* __restrict__ item_emb,
                           float* __restrict__ accU, float* __restrict__ accI) {
  int t = blockIdx.x * blockDim.x + threadIdx.x;
  int total = B * 64;
  if (t < total) {
    int b = t >> 6, d = t & 63;
    accU[t] = user_emb[(size_t)users[b] * 64 + d];
  } else if (t < 2 * total) {
    int t2 = t - total;
    int b = t2 >> 6, d = t2 & 63;
    accI[t2] = item_emb[(size_t)items[b] * 64 + d];
  }
}

__global__ void k_acc_add(const int* __restrict__ users, const int* __restrict__ items, int B,
                          int split, const unsigned short* __restrict__ buf, float w,
                          float* __restrict__ accU, float* __restrict__ accI) {
  int t = blockIdx.x * blockDim.x + threadIdx.x;
  int total = B * 64;
  if (t < total) {
    int b = t >> 6, d = t & 63;
    accU[t] += w * bf2f(buf[(size_t)users[b] * 64 + d]);
  } else if (t < 2 * total) {
    int t2 = t - total;
    int b = t2 >> 6, d = t2 & 63;
    accI[t2] += w * bf2f(buf[(size_t)(split + items[b]) * 64 + d]);
  }
}

// ---------------- fused layer-3 mini-SpMM (only the 8192 sampled rows) ----------------

__global__ __launch_bounds__(256) void k_mini3(
    const int* __restrict__ users, const int* __restrict__ items, int B, int split,
    const unsigned short* __restrict__ ebB,
    const float* __restrict__ e0U, const float* __restrict__ e0I,
    const int* __restrict__ rowptr, const int* __restrict__ cnt,
    const int2* __restrict__ colval,
    float* __restrict__ accU, float* __restrict__ accI) {
  int wave = (int)((blockIdx.x * blockDim.x + threadIdx.x) >> 6);
  int lane = threadIdx.x & 63;
  if (wave >= 2 * B) return;
  int row;
  float* accp;
  if (wave < B) { row = users[wave];              accp = accU + (size_t)wave * 64; }
  else          { row = split + items[wave - B];  accp = accI + (size_t)(wave - B) * 64; }
  int start = __builtin_amdgcn_readfirstlane(rowptr[row]);
  int len   = __builtin_amdgcn_readfirstlane(cnt[row]);
  const int2* cv = colval + start;
  float acc0 = 0.f, acc1 = 0.f;
  int j = 0;
  for (; j + 4 <= len; j += 4) {
#pragma unroll
    for (int u = 0; u < 4; u += 2) {
      int2 ea = cv[j + u];
      int2 eb = cv[j + u + 1];
      acc0 = fmaf(__int_as_float(ea.y), bf2f(ebB[(size_t)ea.x * 64 + lane]), acc0);
      acc1 = fmaf(__int_as_float(eb.y), bf2f(ebB[(size_t)eb.x * 64 + lane]), acc1);
    }
  }
  for (; j < len; j++) {
    int2 e = cv[j];
    acc0 = fmaf(__int_as_float(e.y), bf2f(ebB[(size_t)e.x * 64 + lane]), acc0);
  }
  const float* e0 = (row < split) ? (e0U + (size_t)row * 64) : (e0I + (size_t)(row - split) * 64);
  accp[lane] += (acc0 + acc1) + ALPHA * e0[lane];
}

__global__ void k_dot(const float* __restrict__ accU, const float* __restrict__ accI, int B,
                      float* __restrict__ out) {
  int wave = (int)((blockIdx.x * blockDim.x + threadIdx.x) >> 6);
  int lane = threadIdx.x & 63;
  if (wave >= B) return;
  float p = accU[(size_t)wave * 64 + lane] * accI[(size_t)wave * 64 + lane];
  for (int d = 32; d > 0; d >>= 1) p += __shfl_xor(p, d);
  if (lane == 0) out[wave] = p * (1.f / 16.f);  // (1/4) layer mean x (1/4) weight norm
}

// ---------------- launch ----------------

extern "C" void kernel_launch(void* const* d_in, const int* in_sizes, int n_in,
                              void* d_out, int out_size, void* d_ws, size_t ws_size,
                              hipStream_t stream) {
  const int*   users     = (const int*)d_in[0];
  const int*   items     = (const int*)d_in[1];
  const int*   rows      = (const int*)d_in[2];
  const int*   cols      = (const int*)d_in[3];
  const float* vals      = (const float*)d_in[4];
  const float* user_emb  = (const float*)d_in[5];
  const float* item_emb  = (const float*)d_in[6];
  const float* user_emb0 = (const float*)d_in[7];
  const float* item_emb0 = (const float*)d_in[8];
  float* gamma = (float*)d_out;

  int B   = in_sizes[0];
  int nnz = in_sizes[2];
  int nU  = in_sizes[5] / 64;
  int nI  = in_sizes[6] / 64;
  int N   = nU + nI;
  int nb  = (N + RPB - 1) >> BSHIFT;   // 147 buckets

  char* base = (char*)d_ws;
  unsigned short* ebIn = (unsigned short*)base;          // N*64 bf16
  unsigned short* ebA  = ebIn + (size_t)N * 64;          // N*64 bf16 (layer-1 out)
  unsigned short* ebB  = ebA  + (size_t)N * 64;          // N*64 bf16 (layer-2 out)
  uint2* pPay = (uint2*)ebA;                             // overlay: dead before layer-1 spmm
  char* p = (char*)(ebB + (size_t)N * 64);
  int2* colval = (int2*)p;            p += (size_t)nnz * sizeof(int2);
  int*  rowptr = (int*)p;             p += (size_t)N * sizeof(int);
  int*  cnt    = (int*)p;             p += (size_t)N * sizeof(int);
  int*  bcnt   = (int*)p;             p += MAXB * sizeof(int);
  int*  bptr   = (int*)p;             p += (MAXB + 1) * sizeof(int);
  int*  bcur   = (int*)p;             p += MAXB * sizeof(int);
  float* accU  = (float*)p;           p += (size_t)B * 64 * sizeof(float);
  float* accI  = (float*)p;           p += (size_t)B * 64 * sizeof(float);

  hipMemsetAsync(bcnt, 0, MAXB * sizeof(int), stream);

  const int tpb = 256;
  int nTot = N * 64;
  k_convert<<<(nTot / 4 + tpb - 1) / tpb, tpb, 0, stream>>>(user_emb, item_emb, nU * 64, nTot, ebIn);
  k_bucket_count<<<512, tpb, 0, stream>>>(rows, nnz, bcnt);
  k_scan_buckets<<<1, 256, 0, stream>>>(bcnt, nb, bptr, bcur);
  k_partition<<<(nnz + CHUNK - 1) / CHUNK, tpb, 0, stream>>>(rows, cols, vals, nnz, bcur, pPay);
  k_build_csr<<<nb, tpb, 0, stream>>>(bptr, pPay, N, rowptr, cnt, colval);

  int spmmBlocks = (N + 3) / 4;            // 4 waves (rows) per 256-thread block
  int accThreads = 2 * B * 64;
  int accBlocks = (accThreads + tpb - 1) / tpb;

  // layer 1: src = ebIn, dst = ebA (pPay dead from here), weight 3
  k_spmm<<<spmmBlocks, 256, 0, stream>>>(ebIn, user_emb0, item_emb0, nU,
                                         rowptr, cnt, colval, ebA, N);
  k_acc_init<<<accBlocks, tpb, 0, stream>>>(users, items, B, user_emb, item_emb, accU, accI);
  k_acc_add<<<accBlocks, tpb, 0, stream>>>(users, items, B, nU, ebA, 3.f, accU, accI);

  // layer 2: src = ebA, dst = ebB, weight 2
  k_spmm<<<spmmBlocks, 256, 0, stream>>>(ebA, user_emb0, item_emb0, nU,
                                         rowptr, cnt, colval, ebB, N);
  k_acc_add<<<accBlocks, tpb, 0, stream>>>(users, items, B, nU, ebB, 2.f, accU, accI);

  // layer 3: only the 8192 sampled rows, fused into acc (weight 1)
  k_mini3<<<(2 * B * 64 + tpb - 1) / tpb, tpb, 0, stream>>>(users, items, B, nU, ebB,
                                                            user_emb0, item_emb0,
                                                            rowptr, cnt, colval, accU, accI);

  k_dot<<<(B * 64 + tpb - 1) / tpb, tpb, 0, stream>>>(accU, accI, B, gamma);
}

// Round 5
// 745.316 us; speedup vs baseline: 1.9083x; 1.0175x over previous
//
#include <hip/hip_runtime.h>

#define ALPHA 0.5f
#define BSHIFT 11                // 2048 rows per bucket
#define RPB 2048
#define MAXB 256                 // >= nBuckets (147)
#define CHUNK 8192               // edges per partition block

// ---------------- bf16 helpers ----------------

__device__ __forceinline__ float bf2f(unsigned short u) {
  return __uint_as_float((unsigned)u << 16);
}
__device__ __forceinline__ unsigned short f2bf(float f) {
  unsigned u = __float_as_uint(f);
  u += 0x7fffu + ((u >> 16) & 1u);   // round-to-nearest-even
  return (unsigned short)(u >> 16);
}

// ---------------- input conversion: concat(user_emb,item_emb) -> bf16 ----------------

__global__ __launch_bounds__(256) void k_convert(const float* __restrict__ uE,
                                                 const float* __restrict__ iE,
                                                 int nU64, int nTot,
                                                 unsigned short* __restrict__ out) {
  int i = (blockIdx.x * 256 + threadIdx.x) * 4;
  if (i >= nTot) return;
  const float* src = (i < nU64) ? (uE + i) : (iE + (i - nU64));
  float4 v = *(const float4*)src;
  ushort4 o;
  o.x = f2bf(v.x); o.y = f2bf(v.y); o.z = f2bf(v.z); o.w = f2bf(v.w);
  *(ushort4*)(out + i) = o;
}

// ---------------- Phase 0: bucket counts ----------------

__global__ __launch_bounds__(256) void k_bucket_count(const int* __restrict__ rows, int nnz,
                                                      int* __restrict__ bcnt) {
  __shared__ int lcnt[MAXB];
  int t = threadIdx.x;
  if (t < MAXB) lcnt[t] = 0;
  __syncthreads();
  int stride = gridDim.x * 256;
  for (int e = blockIdx.x * 256 + t; e < nnz; e += stride)
    atomicAdd(&lcnt[rows[e] >> BSHIFT], 1);
  __syncthreads();
  if (t < MAXB) {
    int c = lcnt[t];
    if (c) atomicAdd(&bcnt[t], c);
  }
}

// ---------------- Phase 1: scan bucket counts -> bptr, bcur ----------------

__global__ void k_scan_buckets(const int* __restrict__ bcnt, int nb,
                               int* __restrict__ bptr, int* __restrict__ bcur) {
  __shared__ int s[256];
  int t = threadIdx.x;
  int v = (t < nb) ? bcnt[t] : 0;
  s[t] = v; __syncthreads();
  for (int d = 1; d < 256; d <<= 1) {
    int x = (t >= d) ? s[t - d] : 0;
    __syncthreads();
    s[t] += x;
    __syncthreads();
  }
  if (t < nb) {
    int excl = s[t] - v;
    bptr[t] = excl;
    bcur[t] = excl;
  }
  if (t == 0) bptr[nb] = s[255];   // total
}

// ---------------- Phase 2: partition edges into buckets (packed 8B payload) ----------------

__global__ __launch_bounds__(256) void k_partition(
    const int* __restrict__ rows, const int* __restrict__ cols, const float* __restrict__ vals,
    int nnz, int* __restrict__ bcur, uint2* __restrict__ pPay) {
  __shared__ int lcnt[MAXB];
  __shared__ int lbase[MAXB];
  int t = threadIdx.x;
  if (t < MAXB) lcnt[t] = 0;
  __syncthreads();
  int base = blockIdx.x * CHUNK;
  int end = nnz < base + CHUNK ? nnz : base + CHUNK;
  for (int e = base + t; e < end; e += 256)
    atomicAdd(&lcnt[rows[e] >> BSHIFT], 1);
  __syncthreads();
  if (t < MAXB) {
    int c = lcnt[t];
    lbase[t] = c ? atomicAdd(&bcur[t], c) : 0;
    lcnt[t] = 0;
  }
  __syncthreads();
  for (int e = base + t; e < end; e += 256) {
    int r = rows[e];
    int b = r >> BSHIFT;
    int p = lbase[b] + atomicAdd(&lcnt[b], 1);
    uint2 pay;
    pay.x = ((unsigned)(r & (RPB - 1)) << 20) | (unsigned)cols[e];
    pay.y = __float_as_uint(vals[e]);
    pPay[p] = pay;
  }
}

// ---------------- Phase 3: per-bucket CSR build ----------------

__global__ __launch_bounds__(256) void k_build_csr(
    const int* __restrict__ bptr, const uint2* __restrict__ pPay, int N,
    int* __restrict__ rowptr, int* __restrict__ cnt, int2* __restrict__ colval) {
  __shared__ int lcnt[RPB];        // 8 KB: counts -> cursors
  __shared__ int scanbuf[256];
  int t = threadIdx.x;
  int b = blockIdx.x;
  int r0 = b << BSHIFT;
  int rCount = N - r0; if (rCount > RPB) rCount = RPB;
  int eBeg = bptr[b], eEnd = bptr[b + 1];

  for (int r = t; r < RPB; r += 256) lcnt[r] = 0;
  __syncthreads();
  for (int e = eBeg + t; e < eEnd; e += 256)
    atomicAdd(&lcnt[pPay[e].x >> 20], 1);
  __syncthreads();
  for (int r = t; r < rCount; r += 256) cnt[r0 + r] = lcnt[r];
  int v8[8]; int s = 0;
#pragma unroll
  for (int k = 0; k < 8; k++) {
    int x = lcnt[8 * t + k];
    v8[k] = s; s += x;
  }
  scanbuf[t] = s; __syncthreads();
  for (int d = 1; d < 256; d <<= 1) {
    int x = (t >= d) ? scanbuf[t - d] : 0;
    __syncthreads();
    scanbuf[t] += x;
    __syncthreads();
  }
  int blockExcl = scanbuf[t] - s;
#pragma unroll
  for (int k = 0; k < 8; k++) lcnt[8 * t + k] = blockExcl + v8[k];
  __syncthreads();
  for (int r = t; r < rCount; r += 256) rowptr[r0 + r] = eBeg + lcnt[r];
  __syncthreads();
  for (int e = eBeg + t; e < eEnd; e += 256) {
    uint2 pay = pPay[e];
    int r = (int)(pay.x >> 20);
    int p = eBeg + atomicAdd(&lcnt[r], 1);
    int2 cv; cv.x = (int)(pay.x & 0xFFFFFu); cv.y = (int)pay.y;
    colval[p] = cv;
  }
}

// ---------------- SpMM (bf16): wave = 1 row, 4 quarter-waves = 4 edges/load ----------------
// lane = 16*sub + k: quarter sub handles edge j+sub; lane holds dims 4k..4k+3 (ushort4).

__global__ __launch_bounds__(256) void k_spmm(
    const unsigned short* __restrict__ src,
    const float* __restrict__ e0U, const float* __restrict__ e0I, int split,
    const int* __restrict__ rowptr, const int* __restrict__ cnt,
    const int2* __restrict__ colval,
    unsigned short* __restrict__ dst, int n) {
  int wave = (int)((blockIdx.x * blockDim.x + threadIdx.x) >> 6);
  int lane = threadIdx.x & 63;
  if (wave >= n) return;
  int sub = lane >> 4;
  int k   = lane & 15;
  int row = wave;
  int start = __builtin_amdgcn_readfirstlane(rowptr[row]);
  int len   = __builtin_amdgcn_readfirstlane(cnt[row]);
  const int2* cv = colval + start;
  const unsigned short* srcK = src + (size_t)k * 4;

  float a0 = 0.f, a1 = 0.f, a2 = 0.f, a3 = 0.f;   // bank A
  float b0 = 0.f, b1 = 0.f, b2 = 0.f, b3 = 0.f;   // bank B
  int j = 0;
  for (; j + 16 <= len; j += 16) {
    int2 e0 = cv[j + sub];
    int2 e1 = cv[j + 4 + sub];
    int2 e2 = cv[j + 8 + sub];
    int2 e3 = cv[j + 12 + sub];
    ushort4 x0 = *(const ushort4*)(srcK + (size_t)e0.x * 64);
    ushort4 x1 = *(const ushort4*)(srcK + (size_t)e1.x * 64);
    ushort4 x2 = *(const ushort4*)(srcK + (size_t)e2.x * 64);
    ushort4 x3 = *(const ushort4*)(srcK + (size_t)e3.x * 64);
    float v0 = __int_as_float(e0.y), v1 = __int_as_float(e1.y);
    float v2 = __int_as_float(e2.y), v3 = __int_as_float(e3.y);
    a0 = fmaf(v0, bf2f(x0.x), a0); a1 = fmaf(v0, bf2f(x0.y), a1);
    a2 = fmaf(v0, bf2f(x0.z), a2); a3 = fmaf(v0, bf2f(x0.w), a3);
    b0 = fmaf(v1, bf2f(x1.x), b0); b1 = fmaf(v1, bf2f(x1.y), b1);
    b2 = fmaf(v1, bf2f(x1.z), b2); b3 = fmaf(v1, bf2f(x1.w), b3);
    a0 = fmaf(v2, bf2f(x2.x), a0); a1 = fmaf(v2, bf2f(x2.y), a1);
    a2 = fmaf(v2, bf2f(x2.z), a2); a3 = fmaf(v2, bf2f(x2.w), a3);
    b0 = fmaf(v3, bf2f(x3.x), b0); b1 = fmaf(v3, bf2f(x3.y), b1);
    b2 = fmaf(v3, bf2f(x3.z), b2); b3 = fmaf(v3, bf2f(x3.w), b3);
  }
  for (; j + 4 <= len; j += 4) {
    int2 e = cv[j + sub];
    ushort4 x = *(const ushort4*)(srcK + (size_t)e.x * 64);
    float v = __int_as_float(e.y);
    a0 = fmaf(v, bf2f(x.x), a0); a1 = fmaf(v, bf2f(x.y), a1);
    a2 = fmaf(v, bf2f(x.z), a2); a3 = fmaf(v, bf2f(x.w), a3);
  }
  int m = len - j;
  if (m > 0) {
    int2 e = cv[j + (sub < m ? sub : 0)];
    ushort4 x = *(const ushort4*)(srcK + (size_t)e.x * 64);
    float v = (sub < m) ? __int_as_float(e.y) : 0.f;
    a0 = fmaf(v, bf2f(x.x), a0); a1 = fmaf(v, bf2f(x.y), a1);
    a2 = fmaf(v, bf2f(x.z), a2); a3 = fmaf(v, bf2f(x.w), a3);
  }
  a0 += b0; a1 += b1; a2 += b2; a3 += b3;
  a0 += __shfl_xor(a0, 16); a0 += __shfl_xor(a0, 32);
  a1 += __shfl_xor(a1, 16); a1 += __shfl_xor(a1, 32);
  a2 += __shfl_xor(a2, 16); a2 += __shfl_xor(a2, 32);
  a3 += __shfl_xor(a3, 16); a3 += __shfl_xor(a3, 32);
  if (sub == 0) {
    const float* e0p = (row < split) ? (e0U + (size_t)row * 64)
                                     : (e0I + (size_t)(row - split) * 64);
    float4 ev = *(const float4*)(e0p + k * 4);
    ushort4 o;
    o.x = f2bf(a0 + ALPHA * ev.x);
    o.y = f2bf(a1 + ALPHA * ev.y);
    o.z = f2bf(a2 + ALPHA * ev.z);
    o.w = f2bf(a3 + ALPHA * ev.w);
    *(ushort4*)(dst + (size_t)row * 64 + k * 4) = o;
  }
}

// ---------------- output-row accumulation ----------------

__global__ void k_acc_init(const int* __restrict__ users, const int* __restrict__ items, int B,
                           const float* __restrict__ user_emb, const float* __restrict__ item_emb,
                           float* __restrict__ accU, float* __restrict__ accI) {
  int t = blockIdx.x * blockDim.x + threadIdx.x;
  int total = B * 64;
  if (t < total) {
    int b = t >> 6, d = t & 63;
    accU[t] = user_emb[(size_t)users[b] * 64 + d];
  } else if (t < 2 * total) {
    int t2 = t - total;
    int b = t2 >> 6, d = t2 & 63;
    accI[t2] = item_emb[(size_t)items[b] * 64 + d];
  }
}

__global__ void k_acc_add(const int* __restrict__ users, const int* __restrict__ items, int B,
                          int split, const unsigned short* __restrict__ buf, float w,
                          float* __restrict__ accU, float* __restrict__ accI) {
  int t = blockIdx.x * blockDim.x + threadIdx.x;
  int total = B * 64;
  if (t < total) {
    int b = t >> 6, d = t & 63;
    accU[t] += w * bf2f(buf[(size_t)users[b] * 64 + d]);
  } else if (t < 2 * total) {
    int t2 = t - total;
    int b = t2 >> 6, d = t2 & 63;
    accI[t2] += w * bf2f(buf[(size_t)(split + items[b]) * 64 + d]);
  }
}

// ---------------- fused layer-3 mini-SpMM (only the 8192 sampled rows) ----------------

__global__ __launch_bounds__(256) void k_mini3(
    const int* __restrict__ users, const int* __restrict__ items, int B, int split,
    const unsigned short* __restrict__ ebB,
    const float* __restrict__ e0U, const float* __restrict__ e0I,
    const int* __restrict__ rowptr, const int* __restrict__ cnt,
    const int2* __restrict__ colval,
    float* __restrict__ accU, float* __restrict__ accI) {
  int wave = (int)((blockIdx.x * blockDim.x + threadIdx.x) >> 6);
  int lane = threadIdx.x & 63;
  if (wave >= 2 * B) return;
  int sub = lane >> 4;
  int k   = lane & 15;
  int row;
  float* accp;
  if (wave < B) { row = users[wave];              accp = accU + (size_t)wave * 64; }
  else          { row = split + items[wave - B];  accp = accI + (size_t)(wave - B) * 64; }
  int start = __builtin_amdgcn_readfirstlane(rowptr[row]);
  int len   = __builtin_amdgcn_readfirstlane(cnt[row]);
  const int2* cv = colval + start;
  const unsigned short* srcK = ebB + (size_t)k * 4;
  float a0 = 0.f, a1 = 0.f, a2 = 0.f, a3 = 0.f;
  int j = 0;
  for (; j + 4 <= len; j += 4) {
    int2 e = cv[j + sub];
    ushort4 x = *(const ushort4*)(srcK + (size_t)e.x * 64);
    float v = __int_as_float(e.y);
    a0 = fmaf(v, bf2f(x.x), a0); a1 = fmaf(v, bf2f(x.y), a1);
    a2 = fmaf(v, bf2f(x.z), a2); a3 = fmaf(v, bf2f(x.w), a3);
  }
  int m = len - j;
  if (m > 0) {
    int2 e = cv[j + (sub < m ? sub : 0)];
    ushort4 x = *(const ushort4*)(srcK + (size_t)e.x * 64);
    float v = (sub < m) ? __int_as_float(e.y) : 0.f;
    a0 = fmaf(v, bf2f(x.x), a0); a1 = fmaf(v, bf2f(x.y), a1);
    a2 = fmaf(v, bf2f(x.z), a2); a3 = fmaf(v, bf2f(x.w), a3);
  }
  a0 += __shfl_xor(a0, 16); a0 += __shfl_xor(a0, 32);
  a1 += __shfl_xor(a1, 16); a1 += __shfl_xor(a1, 32);
  a2 += __shfl_xor(a2, 16); a2 += __shfl_xor(a2, 32);
  a3 += __shfl_xor(a3, 16); a3 += __shfl_xor(a3, 32);
  if (sub == 0) {
    const float* e0p = (row < split) ? (e0U + (size_t)row * 64)
                                     : (e0I + (size_t)(row - split) * 64);
    float4 ev = *(const float4*)(e0p + k * 4);
    float4 cur = *(const float4*)(accp + k * 4);
    cur.x += a0 + ALPHA * ev.x;
    cur.y += a1 + ALPHA * ev.y;
    cur.z += a2 + ALPHA * ev.z;
    cur.w += a3 + ALPHA * ev.w;
    *(float4*)(accp + k * 4) = cur;
  }
}

__global__ void k_dot(const float* __restrict__ accU, const float* __restrict__ accI, int B,
                      float* __restrict__ out) {
  int wave = (int)((blockIdx.x * blockDim.x + threadIdx.x) >> 6);
  int lane = threadIdx.x & 63;
  if (wave >= B) return;
  float p = accU[(size_t)wave * 64 + lane] * accI[(size_t)wave * 64 + lane];
  for (int d = 32; d > 0; d >>= 1) p += __shfl_xor(p, d);
  if (lane == 0) out[wave] = p * (1.f / 16.f);  // (1/4) layer mean x (1/4) weight norm
}

// ---------------- launch ----------------

extern "C" void kernel_launch(void* const* d_in, const int* in_sizes, int n_in,
                              void* d_out, int out_size, void* d_ws, size_t ws_size,
                              hipStream_t stream) {
  const int*   users     = (const int*)d_in[0];
  const int*   items     = (const int*)d_in[1];
  const int*   rows      = (const int*)d_in[2];
  const int*   cols      = (const int*)d_in[3];
  const float* vals      = (const float*)d_in[4];
  const float* user_emb  = (const float*)d_in[5];
  const float* item_emb  = (const float*)d_in[6];
  const float* user_emb0 = (const float*)d_in[7];
  const float* item_emb0 = (const float*)d_in[8];
  float* gamma = (float*)d_out;

  int B   = in_sizes[0];
  int nnz = in_sizes[2];
  int nU  = in_sizes[5] / 64;
  int nI  = in_sizes[6] / 64;
  int N   = nU + nI;
  int nb  = (N + RPB - 1) >> BSHIFT;   // 147 buckets

  char* base = (char*)d_ws;
  unsigned short* ebIn = (unsigned short*)base;          // N*64 bf16
  unsigned short* ebA  = ebIn + (size_t)N * 64;          // N*64 bf16 (layer-1 out)
  unsigned short* ebB  = ebA  + (size_t)N * 64;          // N*64 bf16 (layer-2 out)
  uint2* pPay = (uint2*)ebA;                             // overlay: dead before layer-1 spmm
  char* p = (char*)(ebB + (size_t)N * 64);
  int2* colval = (int2*)p;            p += (size_t)nnz * sizeof(int2);
  int*  rowptr = (int*)p;             p += (size_t)N * sizeof(int);
  int*  cnt    = (int*)p;             p += (size_t)N * sizeof(int);
  int*  bcnt   = (int*)p;             p += MAXB * sizeof(int);
  int*  bptr   = (int*)p;             p += (MAXB + 1) * sizeof(int);
  int*  bcur   = (int*)p;             p += MAXB * sizeof(int);
  float* accU  = (float*)p;           p += (size_t)B * 64 * sizeof(float);
  float* accI  = (float*)p;           p += (size_t)B * 64 * sizeof(float);

  hipMemsetAsync(bcnt, 0, MAXB * sizeof(int), stream);

  const int tpb = 256;
  int nTot = N * 64;
  k_convert<<<(nTot / 4 + tpb - 1) / tpb, tpb, 0, stream>>>(user_emb, item_emb, nU * 64, nTot, ebIn);
  k_bucket_count<<<512, tpb, 0, stream>>>(rows, nnz, bcnt);
  k_scan_buckets<<<1, 256, 0, stream>>>(bcnt, nb, bptr, bcur);
  k_partition<<<(nnz + CHUNK - 1) / CHUNK, tpb, 0, stream>>>(rows, cols, vals, nnz, bcur, pPay);
  k_build_csr<<<nb, tpb, 0, stream>>>(bptr, pPay, N, rowptr, cnt, colval);

  int spmmBlocks = (N + 3) / 4;            // 4 waves (rows) per 256-thread block
  int accThreads = 2 * B * 64;
  int accBlocks = (accThreads + tpb - 1) / tpb;

  // layer 1: src = ebIn, dst = ebA (pPay dead from here), weight 3
  k_spmm<<<spmmBlocks, 256, 0, stream>>>(ebIn, user_emb0, item_emb0, nU,
                                         rowptr, cnt, colval, ebA, N);
  k_acc_init<<<accBlocks, tpb, 0, stream>>>(users, items, B, user_emb, item_emb, accU, accI);
  k_acc_add<<<accBlocks, tpb, 0, stream>>>(users, items, B, nU, ebA, 3.f, accU, accI);

  // layer 2: src = ebA, dst = ebB, weight 2
  k_spmm<<<spmmBlocks, 256, 0, stream>>>(ebA, user_emb0, item_emb0, nU,
                                         rowptr, cnt, colval, ebB, N);
  k_acc_add<<<accBlocks, tpb, 0, stream>>>(users, items, B, nU, ebB, 2.f, accU, accI);

  // layer 3: only the 8192 sampled rows, fused into acc (weight 1)
  k_mini3<<<(2 * B * 64 + tpb - 1) / tpb, tpb, 0, stream>>>(users, items, B, nU, ebB,
                                                            user_emb0, item_emb0,
                                                            rowptr, cnt, colval, accU, accI);

  k_dot<<<(B * 64 + tpb - 1) / tpb, tpb, 0, stream>>>(accU, accI, B, gamma);
}

// Round 6
// 711.590 us; speedup vs baseline: 1.9987x; 1.0474x over previous
//
#include <hip/hip_runtime.h>

#define ALPHA 0.5f
#define BSHIFT 11                // 2048 rows per bucket
#define RPB 2048
#define MAXB 256                 // >= nBuckets (147)
#define CHUNK 8192               // edges per partition block

// ---------------- bf16 helpers ----------------

__device__ __forceinline__ float bf2f(unsigned short u) {
  return __uint_as_float((unsigned)u << 16);
}
__device__ __forceinline__ unsigned short f2bf(float f) {
  unsigned u = __float_as_uint(f);
  u += 0x7fffu + ((u >> 16) & 1u);   // round-to-nearest-even
  return (unsigned short)(u >> 16);
}

// ---------------- input conversion: concat(user_emb,item_emb) -> bf16 ----------------

__global__ __launch_bounds__(256) void k_convert(const float* __restrict__ uE,
                                                 const float* __restrict__ iE,
                                                 int nU64, int nTot,
                                                 unsigned short* __restrict__ out) {
  int i = (blockIdx.x * 256 + threadIdx.x) * 4;
  if (i >= nTot) return;
  const float* src = (i < nU64) ? (uE + i) : (iE + (i - nU64));
  float4 v = *(const float4*)src;
  ushort4 o;
  o.x = f2bf(v.x); o.y = f2bf(v.y); o.z = f2bf(v.z); o.w = f2bf(v.w);
  *(ushort4*)(out + i) = o;
}

// ---------------- Phase 0: bucket counts ----------------

__global__ __launch_bounds__(256) void k_bucket_count(const int* __restrict__ rows, int nnz,
                                                      int* __restrict__ bcnt) {
  __shared__ int lcnt[MAXB];
  int t = threadIdx.x;
  if (t < MAXB) lcnt[t] = 0;
  __syncthreads();
  int stride = gridDim.x * 256;
  for (int e = blockIdx.x * 256 + t; e < nnz; e += stride)
    atomicAdd(&lcnt[rows[e] >> BSHIFT], 1);
  __syncthreads();
  if (t < MAXB) {
    int c = lcnt[t];
    if (c) atomicAdd(&bcnt[t], c);
  }
}

// ---------------- Phase 1: scan bucket counts -> bptr, bcur ----------------

__global__ void k_scan_buckets(const int* __restrict__ bcnt, int nb,
                               int* __restrict__ bptr, int* __restrict__ bcur) {
  __shared__ int s[256];
  int t = threadIdx.x;
  int v = (t < nb) ? bcnt[t] : 0;
  s[t] = v; __syncthreads();
  for (int d = 1; d < 256; d <<= 1) {
    int x = (t >= d) ? s[t - d] : 0;
    __syncthreads();
    s[t] += x;
    __syncthreads();
  }
  if (t < nb) {
    int excl = s[t] - v;
    bptr[t] = excl;
    bcur[t] = excl;
  }
  if (t == 0) bptr[nb] = s[255];   // total
}

// ---------------- Phase 2: partition edges into buckets (packed 8B payload) ----------------

__global__ __launch_bounds__(256) void k_partition(
    const int* __restrict__ rows, const int* __restrict__ cols, const float* __restrict__ vals,
    int nnz, int* __restrict__ bcur, uint2* __restrict__ pPay) {
  __shared__ int lcnt[MAXB];
  __shared__ int lbase[MAXB];
  int t = threadIdx.x;
  if (t < MAXB) lcnt[t] = 0;
  __syncthreads();
  int base = blockIdx.x * CHUNK;
  int end = nnz < base + CHUNK ? nnz : base + CHUNK;
  for (int e = base + t; e < end; e += 256)
    atomicAdd(&lcnt[rows[e] >> BSHIFT], 1);
  __syncthreads();
  if (t < MAXB) {
    int c = lcnt[t];
    lbase[t] = c ? atomicAdd(&bcur[t], c) : 0;
    lcnt[t] = 0;
  }
  __syncthreads();
  for (int e = base + t; e < end; e += 256) {
    int r = rows[e];
    int b = r >> BSHIFT;
    int p = lbase[b] + atomicAdd(&lcnt[b], 1);
    uint2 pay;
    pay.x = ((unsigned)(r & (RPB - 1)) << 20) | (unsigned)cols[e];
    pay.y = __float_as_uint(vals[e]);
    pPay[p] = pay;
  }
}

// ---------------- Phase 3: per-bucket CSR build ----------------

__global__ __launch_bounds__(256) void k_build_csr(
    const int* __restrict__ bptr, const uint2* __restrict__ pPay, int N,
    int* __restrict__ rowptr, int* __restrict__ cnt, int2* __restrict__ colval) {
  __shared__ int lcnt[RPB];        // 8 KB: counts -> cursors
  __shared__ int scanbuf[256];
  int t = threadIdx.x;
  int b = blockIdx.x;
  int r0 = b << BSHIFT;
  int rCount = N - r0; if (rCount > RPB) rCount = RPB;
  int eBeg = bptr[b], eEnd = bptr[b + 1];

  for (int r = t; r < RPB; r += 256) lcnt[r] = 0;
  __syncthreads();
  for (int e = eBeg + t; e < eEnd; e += 256)
    atomicAdd(&lcnt[pPay[e].x >> 20], 1);
  __syncthreads();
  for (int r = t; r < rCount; r += 256) cnt[r0 + r] = lcnt[r];
  int v8[8]; int s = 0;
#pragma unroll
  for (int k = 0; k < 8; k++) {
    int x = lcnt[8 * t + k];
    v8[k] = s; s += x;
  }
  scanbuf[t] = s; __syncthreads();
  for (int d = 1; d < 256; d <<= 1) {
    int x = (t >= d) ? scanbuf[t - d] : 0;
    __syncthreads();
    scanbuf[t] += x;
    __syncthreads();
  }
  int blockExcl = scanbuf[t] - s;
#pragma unroll
  for (int k = 0; k < 8; k++) lcnt[8 * t + k] = blockExcl + v8[k];
  __syncthreads();
  for (int r = t; r < rCount; r += 256) rowptr[r0 + r] = eBeg + lcnt[r];
  __syncthreads();
  for (int e = eBeg + t; e < eEnd; e += 256) {
    uint2 pay = pPay[e];
    int r = (int)(pay.x >> 20);
    int p = eBeg + atomicAdd(&lcnt[r], 1);
    int2 cv; cv.x = (int)(pay.x & 0xFFFFFu); cv.y = (int)pay.y;
    colval[p] = cv;
  }
}

// ---------------- SpMM (bf16): quarter-wave (16 lanes) per row ----------------
// wave = 4 independent rows. lane = 16*sub + k: quarter sub owns row wave*4+sub,
// lane holds dims 4k..4k+3 (ushort4). No cross-quarter reduction needed.

__global__ __launch_bounds__(256) void k_spmm(
    const unsigned short* __restrict__ src,
    const float* __restrict__ e0U, const float* __restrict__ e0I, int split,
    const int* __restrict__ rowptr, const int* __restrict__ cnt,
    const int2* __restrict__ colval,
    unsigned short* __restrict__ dst, int n) {
  int wave = (int)((blockIdx.x * blockDim.x + threadIdx.x) >> 6);
  int lane = threadIdx.x & 63;
  int sub = lane >> 4;
  int k   = lane & 15;
  int row = wave * 4 + sub;
  bool valid = row < n;
  int rc = valid ? row : (n - 1);
  int start = rowptr[rc];
  int len   = valid ? cnt[rc] : 0;
  int maxlen = len;
  maxlen = max(maxlen, __shfl_xor(maxlen, 16));
  maxlen = max(maxlen, __shfl_xor(maxlen, 32));
  const int2* cv = colval + start;
  const unsigned short* srcK = src + (size_t)k * 4;
  int lenm1 = (len > 0) ? (len - 1) : 0;

  float a0 = 0.f, a1 = 0.f, a2 = 0.f, a3 = 0.f;
  for (int j = 0; j < maxlen; j += 4) {
#pragma unroll
    for (int u = 0; u < 4; u++) {
      int jj = j + u;
      int jc = (jj < len) ? jj : lenm1;
      int2 e = cv[jc];
      float v = (jj < len) ? __int_as_float(e.y) : 0.f;
      ushort4 x = *(const ushort4*)(srcK + (size_t)e.x * 64);
      a0 = fmaf(v, bf2f(x.x), a0);
      a1 = fmaf(v, bf2f(x.y), a1);
      a2 = fmaf(v, bf2f(x.z), a2);
      a3 = fmaf(v, bf2f(x.w), a3);
    }
  }
  if (valid) {
    const float* e0p = (row < split) ? (e0U + (size_t)row * 64)
                                     : (e0I + (size_t)(row - split) * 64);
    float4 ev = *(const float4*)(e0p + k * 4);
    ushort4 o;
    o.x = f2bf(a0 + ALPHA * ev.x);
    o.y = f2bf(a1 + ALPHA * ev.y);
    o.z = f2bf(a2 + ALPHA * ev.z);
    o.w = f2bf(a3 + ALPHA * ev.w);
    *(ushort4*)(dst + (size_t)row * 64 + k * 4) = o;
  }
}

// ---------------- output-row accumulation ----------------

__global__ void k_acc_init(const int* __restrict__ users, const int* __restrict__ items, int B,
                           const float* __restrict__ user_emb, const float* __restrict__ item_emb,
                           float* __restrict__ accU, float* __restrict__ accI) {
  int t = blockIdx.x * blockDim.x + threadIdx.x;
  int total = B * 64;
  if (t < total) {
    int b = t >> 6, d = t & 63;
    accU[t] = user_emb[(size_t)users[b] * 64 + d];
  } else if (t < 2 * total) {
    int t2 = t - total;
    int b = t2 >> 6, d = t2 & 63;
    accI[t2] = item_emb[(size_t)items[b] * 64 + d];
  }
}

__global__ void k_acc_add(const int* __restrict__ users, const int* __restrict__ items, int B,
                          int split, const unsigned short* __restrict__ buf, float w,
                          float* __restrict__ accU, float* __restrict__ accI) {
  int t = blockIdx.x * blockDim.x + threadIdx.x;
  int total = B * 64;
  if (t < total) {
    int b = t >> 6, d = t & 63;
    accU[t] += w * bf2f(buf[(size_t)users[b] * 64 + d]);
  } else if (t < 2 * total) {
    int t2 = t - total;
    int b = t2 >> 6, d = t2 & 63;
    accI[t2] += w * bf2f(buf[(size_t)(split + items[b]) * 64 + d]);
  }
}

// ---------------- fused layer-3 mini-SpMM (only the 8192 sampled rows) ----------------
// quarter-wave per sampled row, same structure as k_spmm.

__global__ __launch_bounds__(256) void k_mini3(
    const int* __restrict__ users, const int* __restrict__ items, int B, int split,
    const unsigned short* __restrict__ ebB,
    const float* __restrict__ e0U, const float* __restrict__ e0I,
    const int* __restrict__ rowptr, const int* __restrict__ cnt,
    const int2* __restrict__ colval,
    float* __restrict__ accU, float* __restrict__ accI) {
  int wave = (int)((blockIdx.x * blockDim.x + threadIdx.x) >> 6);
  int lane = threadIdx.x & 63;
  int sub = lane >> 4;
  int k   = lane & 15;
  int idx = wave * 4 + sub;
  bool valid = idx < 2 * B;
  int ic = valid ? idx : 0;
  int row;
  float* accp;
  if (ic < B) { row = users[ic];             accp = accU + (size_t)ic * 64; }
  else        { row = split + items[ic - B]; accp = accI + (size_t)(ic - B) * 64; }
  int start = rowptr[row];
  int len   = valid ? cnt[row] : 0;
  int maxlen = len;
  maxlen = max(maxlen, __shfl_xor(maxlen, 16));
  maxlen = max(maxlen, __shfl_xor(maxlen, 32));
  const int2* cv = colval + start;
  const unsigned short* srcK = ebB + (size_t)k * 4;
  int lenm1 = (len > 0) ? (len - 1) : 0;

  float a0 = 0.f, a1 = 0.f, a2 = 0.f, a3 = 0.f;
  for (int j = 0; j < maxlen; j += 4) {
#pragma unroll
    for (int u = 0; u < 4; u++) {
      int jj = j + u;
      int jc = (jj < len) ? jj : lenm1;
      int2 e = cv[jc];
      float v = (jj < len) ? __int_as_float(e.y) : 0.f;
      ushort4 x = *(const ushort4*)(srcK + (size_t)e.x * 64);
      a0 = fmaf(v, bf2f(x.x), a0);
      a1 = fmaf(v, bf2f(x.y), a1);
      a2 = fmaf(v, bf2f(x.z), a2);
      a3 = fmaf(v, bf2f(x.w), a3);
    }
  }
  if (valid) {
    const float* e0p = (row < split) ? (e0U + (size_t)row * 64)
                                     : (e0I + (size_t)(row - split) * 64);
    float4 ev = *(const float4*)(e0p + k * 4);
    float4 cur = *(const float4*)(accp + k * 4);
    cur.x += a0 + ALPHA * ev.x;
    cur.y += a1 + ALPHA * ev.y;
    cur.z += a2 + ALPHA * ev.z;
    cur.w += a3 + ALPHA * ev.w;
    *(float4*)(accp + k * 4) = cur;
  }
}

__global__ void k_dot(const float* __restrict__ accU, const float* __restrict__ accI, int B,
                      float* __restrict__ out) {
  int wave = (int)((blockIdx.x * blockDim.x + threadIdx.x) >> 6);
  int lane = threadIdx.x & 63;
  if (wave >= B) return;
  float p = accU[(size_t)wave * 64 + lane] * accI[(size_t)wave * 64 + lane];
  for (int d = 32; d > 0; d >>= 1) p += __shfl_xor(p, d);
  if (lane == 0) out[wave] = p * (1.f / 16.f);  // (1/4) layer mean x (1/4) weight norm
}

// ---------------- launch ----------------

extern "C" void kernel_launch(void* const* d_in, const int* in_sizes, int n_in,
                              void* d_out, int out_size, void* d_ws, size_t ws_size,
                              hipStream_t stream) {
  const int*   users     = (const int*)d_in[0];
  const int*   items     = (const int*)d_in[1];
  const int*   rows      = (const int*)d_in[2];
  const int*   cols      = (const int*)d_in[3];
  const float* vals      = (const float*)d_in[4];
  const float* user_emb  = (const float*)d_in[5];
  const float* item_emb  = (const float*)d_in[6];
  const float* user_emb0 = (const float*)d_in[7];
  const float* item_emb0 = (const float*)d_in[8];
  float* gamma = (float*)d_out;

  int B   = in_sizes[0];
  int nnz = in_sizes[2];
  int nU  = in_sizes[5] / 64;
  int nI  = in_sizes[6] / 64;
  int N   = nU + nI;
  int nb  = (N + RPB - 1) >> BSHIFT;   // 147 buckets

  char* base = (char*)d_ws;
  unsigned short* ebIn = (unsigned short*)base;          // N*64 bf16
  unsigned short* ebA  = ebIn + (size_t)N * 64;          // N*64 bf16 (layer-1 out)
  unsigned short* ebB  = ebA  + (size_t)N * 64;          // N*64 bf16 (layer-2 out)
  uint2* pPay = (uint2*)ebA;                             // overlay: dead before layer-1 spmm
  char* p = (char*)(ebB + (size_t)N * 64);
  int2* colval = (int2*)p;            p += ((size_t)nnz + 4) * sizeof(int2);
  int*  rowptr = (int*)p;             p += (size_t)N * sizeof(int);
  int*  cnt    = (int*)p;             p += (size_t)N * sizeof(int);
  int*  bcnt   = (int*)p;             p += MAXB * sizeof(int);
  int*  bptr   = (int*)p;             p += (MAXB + 1) * sizeof(int);
  int*  bcur   = (int*)p;             p += MAXB * sizeof(int);
  float* accU  = (float*)p;           p += (size_t)B * 64 * sizeof(float);
  float* accI  = (float*)p;           p += (size_t)B * 64 * sizeof(float);

  hipMemsetAsync(bcnt, 0, MAXB * sizeof(int), stream);

  const int tpb = 256;
  int nTot = N * 64;
  k_convert<<<(nTot / 4 + tpb - 1) / tpb, tpb, 0, stream>>>(user_emb, item_emb, nU * 64, nTot, ebIn);
  k_bucket_count<<<512, tpb, 0, stream>>>(rows, nnz, bcnt);
  k_scan_buckets<<<1, 256, 0, stream>>>(bcnt, nb, bptr, bcur);
  k_partition<<<(nnz + CHUNK - 1) / CHUNK, tpb, 0, stream>>>(rows, cols, vals, nnz, bcur, pPay);
  k_build_csr<<<nb, tpb, 0, stream>>>(bptr, pPay, N, rowptr, cnt, colval);

  int spmmBlocks = (N + 15) / 16;          // 16 rows per 256-thread block (4 waves x 4 rows)
  int accThreads = 2 * B * 64;
  int accBlocks = (accThreads + tpb - 1) / tpb;

  // layer 1: src = ebIn, dst = ebA (pPay dead from here), weight 3
  k_spmm<<<spmmBlocks, 256, 0, stream>>>(ebIn, user_emb0, item_emb0, nU,
                                         rowptr, cnt, colval, ebA, N);
  k_acc_init<<<accBlocks, tpb, 0, stream>>>(users, items, B, user_emb, item_emb, accU, accI);
  k_acc_add<<<accBlocks, tpb, 0, stream>>>(users, items, B, nU, ebA, 3.f, accU, accI);

  // layer 2: src = ebA, dst = ebB, weight 2
  k_spmm<<<spmmBlocks, 256, 0, stream>>>(ebA, user_emb0, item_emb0, nU,
                                         rowptr, cnt, colval, ebB, N);
  k_acc_add<<<accBlocks, tpb, 0, stream>>>(users, items, B, nU, ebB, 2.f, accU, accI);

  // layer 3: only the 8192 sampled rows, fused into acc (weight 1)
  int mBlocks = (2 * B + 15) / 16;
  k_mini3<<<mBlocks, 256, 0, stream>>>(users, items, B, nU, ebB,
                                       user_emb0, item_emb0,
                                       rowptr, cnt, colval, accU, accI);

  k_dot<<<(B * 64 + tpb - 1) / tpb, tpb, 0, stream>>>(accU, accI, B, gamma);
}

// Round 7
// 659.824 us; speedup vs baseline: 2.1555x; 1.0785x over previous
//
#include <hip/hip_runtime.h>

#define ALPHA 0.5f
#define BSHIFT 11                // 2048 rows per bucket
#define RPB 2048
#define MAXB 256                 // >= nBuckets (147)
#define CHUNK 8192               // edges per partition block

// ---------------- bf16 helpers ----------------

__device__ __forceinline__ float bf2f(unsigned short u) {
  return __uint_as_float((unsigned)u << 16);
}
__device__ __forceinline__ unsigned short f2bf(float f) {
  unsigned u = __float_as_uint(f);
  u += 0x7fffu + ((u >> 16) & 1u);   // round-to-nearest-even
  return (unsigned short)(u >> 16);
}

// ---------------- fused: bucket counts (blocks 0..511) + f32->bf16 convert ----------------

__global__ __launch_bounds__(256) void k_conv_bucket(
    const int* __restrict__ rows, int nnz, int* __restrict__ bcnt,
    const float* __restrict__ uE, const float* __restrict__ iE,
    int nU64, int nTot, unsigned short* __restrict__ out) {
  __shared__ int lcnt[MAXB];
  int t = threadIdx.x;
  if (blockIdx.x < 512) {
    if (t < MAXB) lcnt[t] = 0;
    __syncthreads();
    int stride = 512 * 256;
    for (int e = blockIdx.x * 256 + t; e < nnz; e += stride)
      atomicAdd(&lcnt[rows[e] >> BSHIFT], 1);
    __syncthreads();
    if (t < MAXB) {
      int c = lcnt[t];
      if (c) atomicAdd(&bcnt[t], c);
    }
  } else {
    int i = ((int)(blockIdx.x - 512) * 256 + t) * 4;
    if (i >= nTot) return;
    const float* src = (i < nU64) ? (uE + i) : (iE + (i - nU64));
    float4 v = *(const float4*)src;
    ushort4 o;
    o.x = f2bf(v.x); o.y = f2bf(v.y); o.z = f2bf(v.z); o.w = f2bf(v.w);
    *(ushort4*)(out + i) = o;
  }
}

// ---------------- scan bucket counts -> bptr, bcur ----------------

__global__ void k_scan_buckets(const int* __restrict__ bcnt, int nb,
                               int* __restrict__ bptr, int* __restrict__ bcur) {
  __shared__ int s[256];
  int t = threadIdx.x;
  int v = (t < nb) ? bcnt[t] : 0;
  s[t] = v; __syncthreads();
  for (int d = 1; d < 256; d <<= 1) {
    int x = (t >= d) ? s[t - d] : 0;
    __syncthreads();
    s[t] += x;
    __syncthreads();
  }
  if (t < nb) {
    int excl = s[t] - v;
    bptr[t] = excl;
    bcur[t] = excl;
  }
  if (t == 0) bptr[nb] = s[255];   // total
}

// ---------------- partition edges into buckets (packed 8B payload) ----------------

__global__ __launch_bounds__(256) void k_partition(
    const int* __restrict__ rows, const int* __restrict__ cols, const float* __restrict__ vals,
    int nnz, int* __restrict__ bcur, uint2* __restrict__ pPay) {
  __shared__ int lcnt[MAXB];
  __shared__ int lbase[MAXB];
  int t = threadIdx.x;
  if (t < MAXB) lcnt[t] = 0;
  __syncthreads();
  int base = blockIdx.x * CHUNK;
  int end = nnz < base + CHUNK ? nnz : base + CHUNK;
  for (int e = base + t; e < end; e += 256)
    atomicAdd(&lcnt[rows[e] >> BSHIFT], 1);
  __syncthreads();
  if (t < MAXB) {
    int c = lcnt[t];
    lbase[t] = c ? atomicAdd(&bcur[t], c) : 0;
    lcnt[t] = 0;
  }
  __syncthreads();
  for (int e = base + t; e < end; e += 256) {
    int r = rows[e];
    int b = r >> BSHIFT;
    int p = lbase[b] + atomicAdd(&lcnt[b], 1);
    uint2 pay;
    pay.x = ((unsigned)(r & (RPB - 1)) << 20) | (unsigned)cols[e];
    pay.y = __float_as_uint(vals[e]);
    pPay[p] = pay;
  }
}

// ---------------- per-bucket CSR build + degree histogram ----------------

__global__ __launch_bounds__(256) void k_build_csr(
    const int* __restrict__ bptr, const uint2* __restrict__ pPay, int N,
    int* __restrict__ rowptr, int* __restrict__ cnt, int2* __restrict__ colval,
    int* __restrict__ degHist) {
  __shared__ int lcnt[RPB];        // 8 KB: counts -> cursors
  __shared__ int scanbuf[256];
  __shared__ int ldeg[256];
  int t = threadIdx.x;
  int b = blockIdx.x;
  int r0 = b << BSHIFT;
  int rCount = N - r0; if (rCount > RPB) rCount = RPB;
  int eBeg = bptr[b], eEnd = bptr[b + 1];

  for (int r = t; r < RPB; r += 256) lcnt[r] = 0;
  ldeg[t] = 0;
  __syncthreads();
  for (int e = eBeg + t; e < eEnd; e += 256)
    atomicAdd(&lcnt[pPay[e].x >> 20], 1);
  __syncthreads();
  for (int r = t; r < rCount; r += 256) {
    int c = lcnt[r];
    cnt[r0 + r] = c;
    atomicAdd(&ldeg[c < 255 ? c : 255], 1);
  }
  int v8[8]; int s = 0;
#pragma unroll
  for (int k = 0; k < 8; k++) {
    int x = lcnt[8 * t + k];
    v8[k] = s; s += x;
  }
  scanbuf[t] = s; __syncthreads();
  for (int d = 1; d < 256; d <<= 1) {
    int x = (t >= d) ? scanbuf[t - d] : 0;
    __syncthreads();
    scanbuf[t] += x;
    __syncthreads();
  }
  int blockExcl = scanbuf[t] - s;
#pragma unroll
  for (int k = 0; k < 8; k++) lcnt[8 * t + k] = blockExcl + v8[k];
  __syncthreads();
  if (ldeg[t]) atomicAdd(&degHist[t], ldeg[t]);
  for (int r = t; r < rCount; r += 256) rowptr[r0 + r] = eBeg + lcnt[r];
  __syncthreads();
  for (int e = eBeg + t; e < eEnd; e += 256) {
    uint2 pay = pPay[e];
    int r = (int)(pay.x >> 20);
    int p = eBeg + atomicAdd(&lcnt[r], 1);
    int2 cv; cv.x = (int)(pay.x & 0xFFFFFu); cv.y = (int)pay.y;
    colval[p] = cv;
  }
}

// ---------------- degree-bin scan (1 block) + colval pad init ----------------

__global__ void k_degscan(const int* __restrict__ degHist, int* __restrict__ degCur,
                          int2* __restrict__ colval, int nnz) {
  __shared__ int s[256];
  int t = threadIdx.x;
  int v = degHist[t];
  s[t] = v; __syncthreads();
  for (int d = 1; d < 256; d <<= 1) {
    int x = (t >= d) ? s[t - d] : 0;
    __syncthreads();
    s[t] += x;
    __syncthreads();
  }
  degCur[t] = s[t] - v;   // exclusive
  if (t < 4) { int2 z; z.x = 0; z.y = 0; colval[nnz + t] = z; }
}

// ---------------- permute rows into degree-sorted order ----------------
// writes perm[pos]=row, rowptrS[pos], lenS[pos]; LDS-aggregated bin cursors.

__global__ __launch_bounds__(256) void k_permute(
    const int* __restrict__ rowptr, const int* __restrict__ cnt, int N,
    int* __restrict__ degCur,
    int* __restrict__ perm, int* __restrict__ rowptrS, int* __restrict__ lenS) {
  __shared__ int lcnt[256];
  __shared__ int lbase[256];
  int t = threadIdx.x;
  lcnt[t] = 0;
  __syncthreads();
  int base = blockIdx.x * 1024;
  int end = N < base + 1024 ? N : base + 1024;
  for (int r = base + t; r < end; r += 256) {
    int c = cnt[r];
    atomicAdd(&lcnt[c < 255 ? c : 255], 1);
  }
  __syncthreads();
  {
    int c = lcnt[t];
    lbase[t] = c ? atomicAdd(&degCur[t], c) : 0;
    lcnt[t] = 0;
  }
  __syncthreads();
  for (int r = base + t; r < end; r += 256) {
    int c = cnt[r];
    int bin = c < 255 ? c : 255;
    int pos = lbase[bin] + atomicAdd(&lcnt[bin], 1);
    perm[pos] = r;
    rowptrS[pos] = rowptr[r];
    lenS[pos] = c;
  }
}

// ---------------- SpMM core: quarter-wave owns 2 degree-adjacent rows ----------------
// lane = 16*sub + k; quarter sub owns perm slots 2*(wave*4+sub)(+1); lane = dims 4k..4k+3.

__device__ __forceinline__ void spmm_body(
    int gtid,
    const unsigned short* __restrict__ src,
    const float* __restrict__ e0U, const float* __restrict__ e0I, int split,
    const int* __restrict__ perm, const int* __restrict__ rowptrS, const int* __restrict__ lenS,
    const int2* __restrict__ colval,
    unsigned short* __restrict__ dst, int n) {
  int wave = gtid >> 6;
  int lane = gtid & 63;
  int sub = lane >> 4;
  int k   = lane & 15;
  int q = wave * 4 + sub;
  int s0 = 2 * q, s1 = 2 * q + 1;
  bool va = s0 < n, vb = s1 < n;
  int i0 = va ? s0 : 0, i1 = vb ? s1 : 0;
  int row0 = perm[i0], row1 = perm[i1];
  int st0 = rowptrS[i0], st1 = rowptrS[i1];
  int len0 = va ? lenS[i0] : 0, len1 = vb ? lenS[i1] : 0;
  const int2* cv0 = colval + st0;
  const int2* cv1 = colval + st1;
  const unsigned short* srcK = src + (size_t)k * 4;
  int l0m = len0 > 0 ? len0 - 1 : 0;
  int l1m = len1 > 0 ? len1 - 1 : 0;
  int mx = max(len0, len1);

  float p0 = 0.f, p1 = 0.f, p2 = 0.f, p3 = 0.f;   // row0
  float r0a = 0.f, r1a = 0.f, r2a = 0.f, r3a = 0.f; // row1
  for (int j = 0; j < mx; j += 2) {
    int ja = j, jb = j + 1;
    int j0a = ja < l0m ? ja : l0m, j0b = jb < l0m ? jb : l0m;
    int j1a = ja < l1m ? ja : l1m, j1b = jb < l1m ? jb : l1m;
    int2 e0a = cv0[j0a];
    int2 e0b = cv0[j0b];
    int2 e1a = cv1[j1a];
    int2 e1b = cv1[j1b];
    ushort4 x0a = *(const ushort4*)(srcK + (size_t)e0a.x * 64);
    ushort4 x0b = *(const ushort4*)(srcK + (size_t)e0b.x * 64);
    ushort4 x1a = *(const ushort4*)(srcK + (size_t)e1a.x * 64);
    ushort4 x1b = *(const ushort4*)(srcK + (size_t)e1b.x * 64);
    float w0a = ja < len0 ? __int_as_float(e0a.y) : 0.f;
    float w0b = jb < len0 ? __int_as_float(e0b.y) : 0.f;
    float w1a = ja < len1 ? __int_as_float(e1a.y) : 0.f;
    float w1b = jb < len1 ? __int_as_float(e1b.y) : 0.f;
    p0 = fmaf(w0a, bf2f(x0a.x), p0); p1 = fmaf(w0a, bf2f(x0a.y), p1);
    p2 = fmaf(w0a, bf2f(x0a.z), p2); p3 = fmaf(w0a, bf2f(x0a.w), p3);
    p0 = fmaf(w0b, bf2f(x0b.x), p0); p1 = fmaf(w0b, bf2f(x0b.y), p1);
    p2 = fmaf(w0b, bf2f(x0b.z), p2); p3 = fmaf(w0b, bf2f(x0b.w), p3);
    r0a = fmaf(w1a, bf2f(x1a.x), r0a); r1a = fmaf(w1a, bf2f(x1a.y), r1a);
    r2a = fmaf(w1a, bf2f(x1a.z), r2a); r3a = fmaf(w1a, bf2f(x1a.w), r3a);
    r0a = fmaf(w1b, bf2f(x1b.x), r0a); r1a = fmaf(w1b, bf2f(x1b.y), r1a);
    r2a = fmaf(w1b, bf2f(x1b.z), r2a); r3a = fmaf(w1b, bf2f(x1b.w), r3a);
  }
  if (va) {
    const float* e0p = (row0 < split) ? (e0U + (size_t)row0 * 64)
                                      : (e0I + (size_t)(row0 - split) * 64);
    float4 ev = *(const float4*)(e0p + k * 4);
    ushort4 o;
    o.x = f2bf(p0 + ALPHA * ev.x);
    o.y = f2bf(p1 + ALPHA * ev.y);
    o.z = f2bf(p2 + ALPHA * ev.z);
    o.w = f2bf(p3 + ALPHA * ev.w);
    *(ushort4*)(dst + (size_t)row0 * 64 + k * 4) = o;
  }
  if (vb) {
    const float* e0p = (row1 < split) ? (e0U + (size_t)row1 * 64)
                                      : (e0I + (size_t)(row1 - split) * 64);
    float4 ev = *(const float4*)(e0p + k * 4);
    ushort4 o;
    o.x = f2bf(r0a + ALPHA * ev.x);
    o.y = f2bf(r1a + ALPHA * ev.y);
    o.z = f2bf(r2a + ALPHA * ev.z);
    o.w = f2bf(r3a + ALPHA * ev.w);
    *(ushort4*)(dst + (size_t)row1 * 64 + k * 4) = o;
  }
}

__global__ __launch_bounds__(256) void k_spmm(
    const unsigned short* __restrict__ src,
    const float* __restrict__ e0U, const float* __restrict__ e0I, int split,
    const int* __restrict__ perm, const int* __restrict__ rowptrS, const int* __restrict__ lenS,
    const int2* __restrict__ colval,
    unsigned short* __restrict__ dst, int n) {
  spmm_body((int)(blockIdx.x * 256 + threadIdx.x), src, e0U, e0I, split,
            perm, rowptrS, lenS, colval, dst, n);
}

// spmm layer-2 with fused accA: acc = E0_f32[sample] + 3*bf2f(ebA[sample])
__global__ __launch_bounds__(256) void k_spmm2_acc(
    const unsigned short* __restrict__ ebA,
    const float* __restrict__ e0U, const float* __restrict__ e0I, int split,
    const int* __restrict__ perm, const int* __restrict__ rowptrS, const int* __restrict__ lenS,
    const int2* __restrict__ colval,
    unsigned short* __restrict__ ebB, int n, int spmmBlocks,
    const int* __restrict__ users, const int* __restrict__ items, int B,
    const float* __restrict__ user_emb, const float* __restrict__ item_emb,
    float* __restrict__ accU, float* __restrict__ accI) {
  if ((int)blockIdx.x < spmmBlocks) {
    spmm_body((int)(blockIdx.x * 256 + threadIdx.x), ebA, e0U, e0I, split,
              perm, rowptrS, lenS, colval, ebB, n);
  } else {
    int t = ((int)blockIdx.x - spmmBlocks) * 256 + threadIdx.x;
    int total = B * 64;
    if (t < total) {
      int b = t >> 6, d = t & 63;
      size_t idx = (size_t)users[b] * 64 + d;
      accU[t] = user_emb[idx] + 3.f * bf2f(ebA[idx]);
    } else if (t < 2 * total) {
      int t2 = t - total;
      int b = t2 >> 6, d = t2 & 63;
      int r = items[b];
      accI[t2] = item_emb[(size_t)r * 64 + d] + 3.f * bf2f(ebA[(size_t)(split + r) * 64 + d]);
    }
  }
}

// ---------------- fused layer-3 mini-SpMM + 2*E2 term (8192 sampled rows) ----------------

__global__ __launch_bounds__(256) void k_mini3(
    const int* __restrict__ users, const int* __restrict__ items, int B, int split,
    const unsigned short* __restrict__ ebB,
    const float* __restrict__ e0U, const float* __restrict__ e0I,
    const int* __restrict__ rowptr, const int* __restrict__ cnt,
    const int2* __restrict__ colval,
    float* __restrict__ accU, float* __restrict__ accI) {
  int wave = (int)((blockIdx.x * blockDim.x + threadIdx.x) >> 6);
  int lane = threadIdx.x & 63;
  int sub = lane >> 4;
  int k   = lane & 15;
  int idx = wave * 4 + sub;
  bool valid = idx < 2 * B;
  int ic = valid ? idx : 0;
  int row;
  float* accp;
  if (ic < B) { row = users[ic];             accp = accU + (size_t)ic * 64; }
  else        { row = split + items[ic - B]; accp = accI + (size_t)(ic - B) * 64; }
  int start = rowptr[row];
  int len   = valid ? cnt[row] : 0;
  int maxlen = len;
  maxlen = max(maxlen, __shfl_xor(maxlen, 16));
  maxlen = max(maxlen, __shfl_xor(maxlen, 32));
  const int2* cv = colval + start;
  const unsigned short* srcK = ebB + (size_t)k * 4;
  int lenm1 = (len > 0) ? (len - 1) : 0;

  float a0 = 0.f, a1 = 0.f, a2 = 0.f, a3 = 0.f;
  for (int j = 0; j < maxlen; j += 4) {
#pragma unroll
    for (int u = 0; u < 4; u++) {
      int jj = j + u;
      int jc = (jj < len) ? jj : lenm1;
      int2 e = cv[jc];
      float v = (jj < len) ? __int_as_float(e.y) : 0.f;
      ushort4 x = *(const ushort4*)(srcK + (size_t)e.x * 64);
      a0 = fmaf(v, bf2f(x.x), a0);
      a1 = fmaf(v, bf2f(x.y), a1);
      a2 = fmaf(v, bf2f(x.z), a2);
      a3 = fmaf(v, bf2f(x.w), a3);
    }
  }
  if (valid) {
    const float* e0p = (row < split) ? (e0U + (size_t)row * 64)
                                     : (e0I + (size_t)(row - split) * 64);
    float4 ev = *(const float4*)(e0p + k * 4);
    ushort4 x2 = *(const ushort4*)(srcK + (size_t)row * 64);  // E2[row], fused 2x term
    float4 cur = *(const float4*)(accp + k * 4);
    cur.x += a0 + ALPHA * ev.x + 2.f * bf2f(x2.x);
    cur.y += a1 + ALPHA * ev.y + 2.f * bf2f(x2.y);
    cur.z += a2 + ALPHA * ev.z + 2.f * bf2f(x2.z);
    cur.w += a3 + ALPHA * ev.w + 2.f * bf2f(x2.w);
    *(float4*)(accp + k * 4) = cur;
  }
}

__global__ void k_dot(const float* __restrict__ accU, const float* __restrict__ accI, int B,
                      float* __restrict__ out) {
  int wave = (int)((blockIdx.x * blockDim.x + threadIdx.x) >> 6);
  int lane = threadIdx.x & 63;
  if (wave >= B) return;
  float p = accU[(size_t)wave * 64 + lane] * accI[(size_t)wave * 64 + lane];
  for (int d = 32; d > 0; d >>= 1) p += __shfl_xor(p, d);
  if (lane == 0) out[wave] = p * (1.f / 16.f);  // (1/4) layer mean x (1/4) weight norm
}

// ---------------- launch ----------------

extern "C" void kernel_launch(void* const* d_in, const int* in_sizes, int n_in,
                              void* d_out, int out_size, void* d_ws, size_t ws_size,
                              hipStream_t stream) {
  const int*   users     = (const int*)d_in[0];
  const int*   items     = (const int*)d_in[1];
  const int*   rows      = (const int*)d_in[2];
  const int*   cols      = (const int*)d_in[3];
  const float* vals      = (const float*)d_in[4];
  const float* user_emb  = (const float*)d_in[5];
  const float* item_emb  = (const float*)d_in[6];
  const float* user_emb0 = (const float*)d_in[7];
  const float* item_emb0 = (const float*)d_in[8];
  float* gamma = (float*)d_out;

  int B   = in_sizes[0];
  int nnz = in_sizes[2];
  int nU  = in_sizes[5] / 64;
  int nI  = in_sizes[6] / 64;
  int N   = nU + nI;
  int nb  = (N + RPB - 1) >> BSHIFT;   // 147 buckets

  char* base = (char*)d_ws;
  unsigned short* ebIn = (unsigned short*)base;          // N*64 bf16
  unsigned short* ebA  = ebIn + (size_t)N * 64;          // N*64 bf16 (layer-1 out)
  unsigned short* ebB  = ebA  + (size_t)N * 64;          // N*64 bf16 (layer-2 out)
  uint2* pPay = (uint2*)ebA;                             // overlay: dead before layer-1 spmm
  char* p = (char*)(ebB + (size_t)N * 64);
  int2* colval  = (int2*)p;           p += ((size_t)nnz + 4) * sizeof(int2);
  int*  rowptr  = (int*)p;            p += (size_t)N * sizeof(int);
  int*  cnt     = (int*)p;            p += (size_t)N * sizeof(int);
  int*  perm    = (int*)p;            p += (size_t)N * sizeof(int);
  int*  rowptrS = (int*)p;            p += (size_t)N * sizeof(int);
  int*  lenS    = (int*)p;            p += (size_t)N * sizeof(int);
  int*  bcnt    = (int*)p;            p += MAXB * sizeof(int);
  int*  degHist = (int*)p;            p += 256 * sizeof(int);
  int*  bptr    = (int*)p;            p += (MAXB + 1) * sizeof(int);
  int*  bcur    = (int*)p;            p += MAXB * sizeof(int);
  int*  degCur  = (int*)p;            p += 256 * sizeof(int);
  float* accU   = (float*)p;          p += (size_t)B * 64 * sizeof(float);
  float* accI   = (float*)p;          p += (size_t)B * 64 * sizeof(float);

  hipMemsetAsync(bcnt, 0, (MAXB + 256) * sizeof(int), stream);  // bcnt + degHist contiguous

  const int tpb = 256;
  int nTot = N * 64;
  int convBlocks = (nTot / 4 + tpb - 1) / tpb;
  k_conv_bucket<<<512 + convBlocks, tpb, 0, stream>>>(rows, nnz, bcnt,
                                                      user_emb, item_emb, nU * 64, nTot, ebIn);
  k_scan_buckets<<<1, 256, 0, stream>>>(bcnt, nb, bptr, bcur);
  k_partition<<<(nnz + CHUNK - 1) / CHUNK, tpb, 0, stream>>>(rows, cols, vals, nnz, bcur, pPay);
  k_build_csr<<<nb, tpb, 0, stream>>>(bptr, pPay, N, rowptr, cnt, colval, degHist);
  k_degscan<<<1, 256, 0, stream>>>(degHist, degCur, colval, nnz);
  k_permute<<<(N + 1023) / 1024, tpb, 0, stream>>>(rowptr, cnt, N, degCur, perm, rowptrS, lenS);

  // 32 rows per 256-thread block (4 waves x 4 quarters x 2 rows)
  int spmmBlocks = (N + 31) / 32;
  int accBlocks = (2 * B * 64 + tpb - 1) / tpb;

  // layer 1: src = ebIn, dst = ebA (pPay dead from here)
  k_spmm<<<spmmBlocks, tpb, 0, stream>>>(ebIn, user_emb0, item_emb0, nU,
                                         perm, rowptrS, lenS, colval, ebA, N);

  // layer 2 + fused accA (E0 + 3*E1 at sampled rows)
  k_spmm2_acc<<<spmmBlocks + accBlocks, tpb, 0, stream>>>(ebA, user_emb0, item_emb0, nU,
                                                          perm, rowptrS, lenS, colval, ebB, N,
                                                          spmmBlocks, users, items, B,
                                                          user_emb, item_emb, accU, accI);

  // layer 3 sampled rows + fused 2*E2 term
  int mBlocks = (2 * B + 15) / 16;
  k_mini3<<<mBlocks, tpb, 0, stream>>>(users, items, B, nU, ebB,
                                       user_emb0, item_emb0,
                                       rowptr, cnt, colval, accU, accI);

  k_dot<<<(B * 64 + tpb - 1) / tpb, tpb, 0, stream>>>(accU, accI, B, gamma);
}